// Round 1
// baseline (12952.919 us; speedup 1.0000x reference)
//
#include <hip/hip_runtime.h>
#include <math.h>

#define N_NODES 6000
#define N_EDGES 192000
#define H 128
#define NHEADS 4
#define HCAT (H * (NHEADS + 1))   // 640
#define TQ 32
#define TK 32
#define QSTR (H + 1)              // 129: breaks stride-128 bank conflicts

// ---------------- degree / norm ----------------
__global__ void fill_ones(float* deg) {
    int i = blockIdx.x * 256 + threadIdx.x;
    if (i < N_NODES) deg[i] = 1.0f;   // self loop
}

__global__ void deg_edges(const int* __restrict__ edges, float* deg) {
    int e = blockIdx.x * 256 + threadIdx.x;
    if (e < N_EDGES) atomicAdd(&deg[edges[N_EDGES + e]], 1.0f);  // target = edges[1]
}

__global__ void dinv_kernel(const float* __restrict__ deg, float* __restrict__ dinv) {
    int i = blockIdx.x * 256 + threadIdx.x;
    if (i < N_NODES) dinv[i] = 1.0f / sqrtf(deg[i]);
}

// ---------------- GCN layer pieces ----------------
// hw = h_in @ W   ((N,in_dim) @ (in_dim,H)); grid=N, block=H
__global__ __launch_bounds__(H)
void gcn_gemm(const float* __restrict__ hin, const float* __restrict__ W,
              float* __restrict__ hw, int in_dim) {
    __shared__ float sh[H];
    int n = blockIdx.x, f = threadIdx.x;
    if (f < in_dim) sh[f] = hin[n * in_dim + f];
    __syncthreads();
    float acc = 0.f;
    for (int d = 0; d < in_dim; ++d) acc += sh[d] * W[d * H + f];
    hw[n * H + f] = acc;
}

// agg = hw * dinv^2 (self-loop contribution, also zero-initializes)
__global__ void agg_init(const float* __restrict__ hw, const float* __restrict__ dinv,
                         float* __restrict__ agg) {
    int i = blockIdx.x * 256 + threadIdx.x;
    if (i < N_NODES * H) {
        int n = i >> 7;
        float di = dinv[n];
        agg[i] = hw[i] * di * di;
    }
}

// agg[tgt] += hw[src] * dinv[src]*dinv[tgt], one thread per (edge, feature)
__global__ void agg_edges(const int* __restrict__ edges, const float* __restrict__ hw,
                          const float* __restrict__ dinv, float* __restrict__ agg) {
    int idx = blockIdx.x * 256 + threadIdx.x;
    if (idx >= N_EDGES * H) return;
    int e = idx >> 7, f = idx & (H - 1);
    int s = edges[e];
    int t = edges[N_EDGES + e];
    float nrm = dinv[s] * dinv[t];
    atomicAdd(&agg[t * H + f], hw[s * H + f] * nrm);
}

__global__ void bias_relu(const float* __restrict__ agg, const float* __restrict__ b,
                          float* __restrict__ hout) {
    int i = blockIdx.x * 256 + threadIdx.x;
    if (i < N_NODES * H) {
        float v = agg[i] + b[i & (H - 1)];
        hout[i] = v > 0.f ? v : 0.f;
    }
}

// ---------------- attention q/k projections ----------------
// grid (N, NHEADS, 2): z=0 -> q from xr, z=1 -> k from xg
__global__ __launch_bounds__(H)
void qk_kernel(const float* __restrict__ xr, const float* __restrict__ xg,
               const float* __restrict__ Wa, const float* __restrict__ ba,
               float* __restrict__ q4, float* __restrict__ k4) {
    __shared__ float sh[H];
    int n = blockIdx.x, head = blockIdx.y, which = blockIdx.z, f = threadIdx.x;
    const float* src = which ? xg : xr;
    float* dst = which ? k4 : q4;
    sh[f] = src[n * H + f];
    __syncthreads();
    const float* W = Wa + (size_t)head * H * H;
    float acc = ba[head * H + f];
    for (int d = 0; d < H; ++d) acc += sh[d] * W[d * H + f];
    dst[((size_t)head * N_NODES + n) * H + f] = acc;
}

__global__ void copy_xr(const float* __restrict__ xr, float* __restrict__ hcat) {
    int i = blockIdx.x * 256 + threadIdx.x;
    if (i < N_NODES * H) {
        int n = i >> 7, f = i & (H - 1);
        hcat[(size_t)n * HCAT + f] = xr[i];
    }
}

// ---------------- flash attention (fp32) ----------------
// grid (ceil(N/TQ), NHEADS), block 256. Writes head output into hcat cols
// [H + head*H, H + (head+1)*H).
__global__ __launch_bounds__(256)
void attn_kernel(const float* __restrict__ q4, const float* __restrict__ k4,
                 const float* __restrict__ xg, float* __restrict__ hcat) {
    __shared__ float Qs[TQ][QSTR];
    __shared__ float Ks[TK][QSTR];
    __shared__ float Vs[TK][QSTR];
    __shared__ float Ss[TQ][TK + 1];
    __shared__ float Ps[TQ][TK + 1];

    const int head = blockIdx.y;
    const int q0 = blockIdx.x * TQ;
    const int t = threadIdx.x;
    const float* q = q4 + (size_t)head * N_NODES * H;
    const float* k = k4 + (size_t)head * N_NODES * H;

    for (int i = t; i < TQ * H; i += 256) {
        int r = i >> 7, d = i & (H - 1);
        Qs[r][d] = (q0 + r < N_NODES) ? q[(size_t)(q0 + r) * H + d] : 0.f;
    }

    float O[16];
#pragma unroll
    for (int u = 0; u < 16; ++u) O[u] = 0.f;
    float m = -1e30f, l = 0.f;
    const int qi = t >> 3;             // owned query row (8 threads per row)
    const int dbase = (t & 7) * 16;    // owned 16 output dims

    for (int k0 = 0; k0 < N_NODES; k0 += TK) {
        int kn = (N_NODES - k0 < TK) ? (N_NODES - k0) : TK;
        __syncthreads();   // prev-iter Vs reads done before overwrite (also covers Qs on iter 0)
        for (int i = t; i < TK * H; i += 256) {
            int r = i >> 7, d = i & (H - 1);
            bool ok = (k0 + r) < N_NODES;
            Ks[r][d] = ok ? k[(size_t)(k0 + r) * H + d] : 0.f;
            Vs[r][d] = ok ? xg[(size_t)(k0 + r) * H + d] : 0.f;
        }
        __syncthreads();

        // S = Q K^T: thread computes 4 rows for one ki
        {
            int ki = t & 31;
            int qb = (t >> 5) * 4;
#pragma unroll
            for (int j = 0; j < 4; ++j) {
                int qr = qb + j;
                float s = 0.f;
                for (int d = 0; d < H; ++d) s += Qs[qr][d] * Ks[ki][d];
                Ss[qr][ki] = (ki < kn) ? s : -1e30f;
            }
        }
        __syncthreads();

        // online softmax stats (replicated across the 8 threads of a row)
        float mtile = -1e30f;
        for (int ki2 = 0; ki2 < TK; ++ki2) mtile = fmaxf(mtile, Ss[qi][ki2]);
        float mnew = fmaxf(m, mtile);
        float alpha = expf(m - mnew);
        {
            int g = t & 7;
#pragma unroll
            for (int jj = 0; jj < 4; ++jj) {
                int ki2 = g * 4 + jj;
                Ps[qi][ki2] = expf(Ss[qi][ki2] - mnew);
            }
        }
        __syncthreads();

        float psum = 0.f;
#pragma unroll
        for (int u = 0; u < 16; ++u) O[u] *= alpha;
        for (int ki2 = 0; ki2 < kn; ++ki2) {
            float p = Ps[qi][ki2];
            psum += p;
#pragma unroll
            for (int u = 0; u < 16; ++u) O[u] += p * Vs[ki2][dbase + u];
        }
        l = l * alpha + psum;
        m = mnew;
    }

    if (q0 + qi < N_NODES) {
        float inv = 1.f / l;
        float* dst = hcat + (size_t)(q0 + qi) * HCAT + H + head * H + dbase;
#pragma unroll
        for (int u = 0; u < 16; ++u) dst[u] = O[u] * inv;
    }
}

// ---------------- fused decoder MLP ----------------
// grid=N, block=H
__global__ __launch_bounds__(H)
void decoder(const float* __restrict__ hcat,
             const float* __restrict__ Wd0, const float* __restrict__ bd0,
             const float* __restrict__ Wd, const float* __restrict__ bd,
             const float* __restrict__ Wout, const float* __restrict__ bout,
             float* __restrict__ out) {
    __shared__ float s0[HCAT];
    __shared__ float s1[H];
    __shared__ float s2[H];
    int n = blockIdx.x, f = threadIdx.x;
    for (int d = f; d < HCAT; d += H) s0[d] = hcat[(size_t)n * HCAT + d];
    __syncthreads();
    float a = bd0[f];
    for (int d = 0; d < HCAT; ++d) a += s0[d] * Wd0[d * H + f];
    s1[f] = fmaxf(a, 0.f);
    __syncthreads();
    a = bd[f];
    for (int d = 0; d < H; ++d) a += s1[d] * Wd[d * H + f];
    s2[f] = fmaxf(a, 0.f);
    __syncthreads();
    a = bd[H + f];
    for (int d = 0; d < H; ++d) a += s2[d] * Wd[H * H + d * H + f];
    __syncthreads();           // everyone done reading s1 (from layer 1) & s2
    s1[f] = fmaxf(a, 0.f);
    __syncthreads();
    if (f < 3) {
        float o = bout[f];
        for (int d = 0; d < H; ++d) o += s1[d] * Wout[d * 3 + f];
        out[n * 3 + f] = o;
    }
}

// ---------------- launch ----------------
extern "C" void kernel_launch(void* const* d_in, const int* in_sizes, int n_in,
                              void* d_out, int out_size, void* d_ws, size_t ws_size,
                              hipStream_t stream) {
    const float* x_rest = (const float*)d_in[0];
    const float* x_rig  = (const float*)d_in[1];
    const int*   e_rest = (const int*)d_in[2];
    const int*   e_rig  = (const int*)d_in[3];
    const float* Wr0 = (const float*)d_in[4];
    const float* br0 = (const float*)d_in[5];
    const float* Wr  = (const float*)d_in[6];
    const float* br  = (const float*)d_in[7];
    const float* Wg0 = (const float*)d_in[8];
    const float* bg0 = (const float*)d_in[9];
    const float* Wg  = (const float*)d_in[10];
    const float* bg  = (const float*)d_in[11];
    const float* Wa  = (const float*)d_in[12];
    const float* ba  = (const float*)d_in[13];
    const float* Wd0 = (const float*)d_in[14];
    const float* bd0 = (const float*)d_in[15];
    const float* Wd  = (const float*)d_in[16];
    const float* bd  = (const float*)d_in[17];
    const float* Wout = (const float*)d_in[18];
    const float* bout = (const float*)d_in[19];
    float* out = (float*)d_out;

    const size_t NH = (size_t)N_NODES * H;
    float* ws = (float*)d_ws;
    float* dinv_r = ws;
    float* dinv_g = dinv_r + N_NODES;
    float* deg    = dinv_g + N_NODES;
    float* hw     = deg + N_NODES;
    float* agg    = hw + NH;
    float* h0     = agg + NH;
    float* h1     = h0 + NH;
    float* xr     = h1 + NH;
    float* xg     = xr + NH;
    float* q4     = xg + NH;
    float* k4     = q4 + 4 * NH;
    float* hcat   = k4 + 4 * NH;
    // total: 3*N + 14*N*H + N*640 floats ~= 58.5 MB

    const int gN   = (N_NODES + 255) / 256;
    const int gE   = (N_EDGES + 255) / 256;
    const int gNH  = (N_NODES * H + 255) / 256;
    const int gEH  = (N_EDGES * H + 255) / 256;

    auto layer = [&](const float* hin, int in_dim, const float* W, const float* b,
                     float* hout, const int* edges, const float* dinv) {
        gcn_gemm<<<N_NODES, H, 0, stream>>>(hin, W, hw, in_dim);
        agg_init<<<gNH, 256, 0, stream>>>(hw, dinv, agg);
        agg_edges<<<gEH, 256, 0, stream>>>(edges, hw, dinv, agg);
        bias_relu<<<gNH, 256, 0, stream>>>(agg, b, hout);
    };

    // degrees + norms
    fill_ones<<<gN, 256, 0, stream>>>(deg);
    deg_edges<<<gE, 256, 0, stream>>>(e_rest, deg);
    dinv_kernel<<<gN, 256, 0, stream>>>(deg, dinv_r);
    fill_ones<<<gN, 256, 0, stream>>>(deg);
    deg_edges<<<gE, 256, 0, stream>>>(e_rig, deg);
    dinv_kernel<<<gN, 256, 0, stream>>>(deg, dinv_g);

    // resting encoder
    layer(x_rest, 3, Wr0, br0, h0, e_rest, dinv_r);
    layer(h0, H, Wr, br, h1, e_rest, dinv_r);
    layer(h1, H, Wr + H * H, br + H, xr, e_rest, dinv_r);
    // rigid encoder
    layer(x_rig, 3, Wg0, bg0, h0, e_rig, dinv_g);
    layer(h0, H, Wg, bg, h1, e_rig, dinv_g);
    layer(h1, H, Wg + H * H, bg + H, xg, e_rig, dinv_g);

    // attention projections
    qk_kernel<<<dim3(N_NODES, NHEADS, 2), H, 0, stream>>>(xr, xg, Wa, ba, q4, k4);
    copy_xr<<<gNH, 256, 0, stream>>>(xr, hcat);
    attn_kernel<<<dim3((N_NODES + TQ - 1) / TQ, NHEADS), 256, 0, stream>>>(q4, k4, xg, hcat);

    // decoder
    decoder<<<N_NODES, H, 0, stream>>>(hcat, Wd0, bd0, Wd, bd, Wout, bout, out);
}

// Round 2
// 4246.738 us; speedup vs baseline: 3.0501x; 3.0501x over previous
//
#include <hip/hip_runtime.h>
#include <math.h>

#define N_NODES 6000
#define N_EDGES 192000
#define H 128
#define NHEADS 4
#define HCAT (H * (NHEADS + 1))   // 640

// attention tile config
#define TQ 48
#define TK 32
#define LSTR 132                  // 132 floats = 33 quad-banks == 1 mod 32: conflict-free
#define PSTR 36

// ---------------- degree / norm ----------------
__global__ void fill_ones(float* deg) {
    int i = blockIdx.x * 256 + threadIdx.x;
    if (i < N_NODES) deg[i] = 1.0f;   // self loop
}

__global__ void deg_edges(const int* __restrict__ edges, float* deg) {
    int e = blockIdx.x * 256 + threadIdx.x;
    if (e < N_EDGES) atomicAdd(&deg[edges[N_EDGES + e]], 1.0f);  // target = edges[1]
}

__global__ void dinv_kernel(const float* __restrict__ deg, float* __restrict__ dinv) {
    int i = blockIdx.x * 256 + threadIdx.x;
    if (i < N_NODES) dinv[i] = 1.0f / sqrtf(deg[i]);
}

// ---------------- GCN layer pieces ----------------
// hw = h_in @ W   ((N,in_dim) @ (in_dim,H)); grid=N, block=H
__global__ __launch_bounds__(H)
void gcn_gemm(const float* __restrict__ hin, const float* __restrict__ W,
              float* __restrict__ hw, int in_dim) {
    __shared__ float sh[H];
    int n = blockIdx.x, f = threadIdx.x;
    if (f < in_dim) sh[f] = hin[n * in_dim + f];
    __syncthreads();
    float acc = 0.f;
    for (int d = 0; d < in_dim; ++d) acc += sh[d] * W[d * H + f];
    hw[n * H + f] = acc;
}

// agg = hw * dinv^2 (self-loop contribution, also zero-initializes)
__global__ void agg_init(const float* __restrict__ hw, const float* __restrict__ dinv,
                         float* __restrict__ agg) {
    int i = blockIdx.x * 256 + threadIdx.x;
    if (i < N_NODES * H) {
        int n = i >> 7;
        float di = dinv[n];
        agg[i] = hw[i] * di * di;
    }
}

// agg[tgt] += hw[src] * dinv[src]*dinv[tgt], one thread per (edge, 4 features)
__global__ void agg_edges(const int* __restrict__ edges, const float* __restrict__ hw,
                          const float* __restrict__ dinv, float* __restrict__ agg) {
    int idx = blockIdx.x * 256 + threadIdx.x;
    if (idx >= N_EDGES * (H / 4)) return;
    int e = idx >> 5, f4 = (idx & 31) << 2;
    int s = edges[e];
    int t = edges[N_EDGES + e];
    float nrm = dinv[s] * dinv[t];
    float4 hv = *(const float4*)&hw[(size_t)s * H + f4];
    float* a = &agg[(size_t)t * H + f4];
    atomicAdd(a + 0, hv.x * nrm);
    atomicAdd(a + 1, hv.y * nrm);
    atomicAdd(a + 2, hv.z * nrm);
    atomicAdd(a + 3, hv.w * nrm);
}

__global__ void bias_relu(const float* __restrict__ agg, const float* __restrict__ b,
                          float* __restrict__ hout) {
    int i = blockIdx.x * 256 + threadIdx.x;
    if (i < N_NODES * H) {
        float v = agg[i] + b[i & (H - 1)];
        hout[i] = v > 0.f ? v : 0.f;
    }
}

// ---------------- attention q/k projections ----------------
// grid (N, NHEADS, 2): z=0 -> q from xr, z=1 -> k from xg
__global__ __launch_bounds__(H)
void qk_kernel(const float* __restrict__ xr, const float* __restrict__ xg,
               const float* __restrict__ Wa, const float* __restrict__ ba,
               float* __restrict__ q4, float* __restrict__ k4) {
    __shared__ float sh[H];
    int n = blockIdx.x, head = blockIdx.y, which = blockIdx.z, f = threadIdx.x;
    const float* src = which ? xg : xr;
    float* dst = which ? k4 : q4;
    sh[f] = src[n * H + f];
    __syncthreads();
    const float* W = Wa + (size_t)head * H * H;
    float acc = ba[head * H + f];
    for (int d = 0; d < H; ++d) acc += sh[d] * W[d * H + f];
    dst[((size_t)head * N_NODES + n) * H + f] = acc;
}

__global__ void copy_xr(const float* __restrict__ xr, float* __restrict__ hcat) {
    int i = blockIdx.x * 256 + threadIdx.x;
    if (i < N_NODES * H) {
        int n = i >> 7, f = i & (H - 1);
        hcat[(size_t)n * HCAT + f] = xr[i];
    }
}

// ---------------- flash attention (fp32, register-tiled) ----------------
// grid (125, NHEADS), block 256. Thread layout: trow=t>>4 (16), tcol=t&15 (16).
// S-phase: thread computes rows 3*trow..+2, cols 2*tcol..+1 (3x2 microtile).
// PV-phase: thread owns rows 3*trow..+2, output cols 8*tcol..+7 (3x8 microtile).
// All LDS reads are ds_read_b128 on stride-132 rows (quad-bank stride 1 mod 32).
__global__ __launch_bounds__(256, 2)
void attn_kernel(const float* __restrict__ q4, const float* __restrict__ k4,
                 const float* __restrict__ xg, float* __restrict__ hcat) {
    __shared__ float Qs[TQ * LSTR];
    __shared__ float Ks[TK * LSTR];
    __shared__ float Vs[TK * LSTR];
    __shared__ float Ps[TQ * PSTR];

    const int head = blockIdx.y;
    const int q0 = blockIdx.x * TQ;     // 125*48 == 6000 exactly: all q rows valid
    const int t = threadIdx.x;
    const int trow = t >> 4;
    const int tcol = t & 15;
    const float* q = q4 + (size_t)head * N_NODES * H;
    const float* k = k4 + (size_t)head * N_NODES * H;

    // load Q tile (48 rows x 128 = 1536 float4, 6 per thread)
    for (int i = t; i < TQ * (H / 4); i += 256) {
        int r = i >> 5, c4 = (i & 31) << 2;
        *(float4*)&Qs[r * LSTR + c4] = *(const float4*)&q[(size_t)(q0 + r) * H + c4];
    }

    float O[3][8];
    float m[3], l[3];
#pragma unroll
    for (int j = 0; j < 3; ++j) {
        m[j] = -1e30f; l[j] = 0.f;
#pragma unroll
        for (int u = 0; u < 8; ++u) O[j][u] = 0.f;
    }

    for (int k0 = 0; k0 < N_NODES; k0 += TK) {
        __syncthreads();   // prev PV done reading Ks/Vs (no-op cost on iter 0)
        for (int i = t; i < TK * (H / 4); i += 256) {
            int r = i >> 5, c4 = (i & 31) << 2;
            bool ok = (k0 + r) < N_NODES;
            float4 kv = ok ? *(const float4*)&k[(size_t)(k0 + r) * H + c4] : float4{0.f, 0.f, 0.f, 0.f};
            float4 vv = ok ? *(const float4*)&xg[(size_t)(k0 + r) * H + c4] : float4{0.f, 0.f, 0.f, 0.f};
            *(float4*)&Ks[r * LSTR + c4] = kv;
            *(float4*)&Vs[r * LSTR + c4] = vv;
        }
        __syncthreads();

        // ---- S = Q K^T (3x2 microtile, b128 reads) ----
        float s0[3] = {0.f, 0.f, 0.f};
        float s1[3] = {0.f, 0.f, 0.f};
#pragma unroll 4
        for (int d4 = 0; d4 < H / 4; ++d4) {
            float4 kf0 = *(float4*)&Ks[(tcol * 2 + 0) * LSTR + d4 * 4];
            float4 kf1 = *(float4*)&Ks[(tcol * 2 + 1) * LSTR + d4 * 4];
#pragma unroll
            for (int j = 0; j < 3; ++j) {
                float4 qf = *(float4*)&Qs[(trow * 3 + j) * LSTR + d4 * 4];
                s0[j] += qf.x * kf0.x + qf.y * kf0.y + qf.z * kf0.z + qf.w * kf0.w;
                s1[j] += qf.x * kf1.x + qf.y * kf1.y + qf.z * kf1.z + qf.w * kf1.w;
            }
        }

        // ---- online softmax (stats via 16-lane shfl butterflies) ----
        bool v0 = (k0 + tcol * 2 + 0) < N_NODES;
        bool v1 = (k0 + tcol * 2 + 1) < N_NODES;
        float alpha[3];
#pragma unroll
        for (int j = 0; j < 3; ++j) {
            float a0 = v0 ? s0[j] : -1e30f;
            float a1 = v1 ? s1[j] : -1e30f;
            float mx = fmaxf(a0, a1);
            mx = fmaxf(mx, __shfl_xor(mx, 1));
            mx = fmaxf(mx, __shfl_xor(mx, 2));
            mx = fmaxf(mx, __shfl_xor(mx, 4));
            mx = fmaxf(mx, __shfl_xor(mx, 8));
            float mn = fmaxf(m[j], mx);
            alpha[j] = expf(m[j] - mn);
            float p0 = expf(a0 - mn);
            float p1 = expf(a1 - mn);
            float ps = p0 + p1;
            ps += __shfl_xor(ps, 1);
            ps += __shfl_xor(ps, 2);
            ps += __shfl_xor(ps, 4);
            ps += __shfl_xor(ps, 8);
            l[j] = l[j] * alpha[j] + ps;
            m[j] = mn;
            Ps[(trow * 3 + j) * PSTR + tcol * 2 + 0] = p0;
            Ps[(trow * 3 + j) * PSTR + tcol * 2 + 1] = p1;
        }
        __syncthreads();

        // ---- O = O*alpha + P V (3x8 microtile, b128 reads) ----
#pragma unroll
        for (int j = 0; j < 3; ++j)
#pragma unroll
            for (int u = 0; u < 8; ++u) O[j][u] *= alpha[j];

#pragma unroll 2
        for (int k4i = 0; k4i < TK / 4; ++k4i) {
            float4 pf[3];
#pragma unroll
            for (int j = 0; j < 3; ++j)
                pf[j] = *(float4*)&Ps[(trow * 3 + j) * PSTR + k4i * 4];
#pragma unroll
            for (int kk = 0; kk < 4; ++kk) {
                float4 va = *(float4*)&Vs[(k4i * 4 + kk) * LSTR + tcol * 8];
                float4 vb = *(float4*)&Vs[(k4i * 4 + kk) * LSTR + tcol * 8 + 4];
#pragma unroll
                for (int j = 0; j < 3; ++j) {
                    float p = ((const float*)&pf[j])[kk];
                    O[j][0] += p * va.x; O[j][1] += p * va.y;
                    O[j][2] += p * va.z; O[j][3] += p * va.w;
                    O[j][4] += p * vb.x; O[j][5] += p * vb.y;
                    O[j][6] += p * vb.z; O[j][7] += p * vb.w;
                }
            }
        }
    }

    // ---- epilogue: normalize + store into hcat ----
#pragma unroll
    for (int j = 0; j < 3; ++j) {
        float inv = 1.f / l[j];
        int n = q0 + trow * 3 + j;
        float* dst = &hcat[(size_t)n * HCAT + H + head * H + tcol * 8];
        float4 oa = {O[j][0] * inv, O[j][1] * inv, O[j][2] * inv, O[j][3] * inv};
        float4 ob = {O[j][4] * inv, O[j][5] * inv, O[j][6] * inv, O[j][7] * inv};
        *(float4*)dst = oa;
        *(float4*)(dst + 4) = ob;
    }
}

// ---------------- fused decoder MLP ----------------
// grid=N, block=H
__global__ __launch_bounds__(H)
void decoder(const float* __restrict__ hcat,
             const float* __restrict__ Wd0, const float* __restrict__ bd0,
             const float* __restrict__ Wd, const float* __restrict__ bd,
             const float* __restrict__ Wout, const float* __restrict__ bout,
             float* __restrict__ out) {
    __shared__ float s0[HCAT];
    __shared__ float s1[H];
    __shared__ float s2[H];
    int n = blockIdx.x, f = threadIdx.x;
    for (int d = f; d < HCAT; d += H) s0[d] = hcat[(size_t)n * HCAT + d];
    __syncthreads();
    float a = bd0[f];
    for (int d = 0; d < HCAT; ++d) a += s0[d] * Wd0[d * H + f];
    s1[f] = fmaxf(a, 0.f);
    __syncthreads();
    a = bd[f];
    for (int d = 0; d < H; ++d) a += s1[d] * Wd[d * H + f];
    s2[f] = fmaxf(a, 0.f);
    __syncthreads();
    a = bd[H + f];
    for (int d = 0; d < H; ++d) a += s2[d] * Wd[H * H + d * H + f];
    __syncthreads();           // everyone done reading s1 & s2
    s1[f] = fmaxf(a, 0.f);
    __syncthreads();
    if (f < 3) {
        float o = bout[f];
        for (int d = 0; d < H; ++d) o += s1[d] * Wout[d * 3 + f];
        out[n * 3 + f] = o;
    }
}

// ---------------- launch ----------------
extern "C" void kernel_launch(void* const* d_in, const int* in_sizes, int n_in,
                              void* d_out, int out_size, void* d_ws, size_t ws_size,
                              hipStream_t stream) {
    const float* x_rest = (const float*)d_in[0];
    const float* x_rig  = (const float*)d_in[1];
    const int*   e_rest = (const int*)d_in[2];
    const int*   e_rig  = (const int*)d_in[3];
    const float* Wr0 = (const float*)d_in[4];
    const float* br0 = (const float*)d_in[5];
    const float* Wr  = (const float*)d_in[6];
    const float* br  = (const float*)d_in[7];
    const float* Wg0 = (const float*)d_in[8];
    const float* bg0 = (const float*)d_in[9];
    const float* Wg  = (const float*)d_in[10];
    const float* bg  = (const float*)d_in[11];
    const float* Wa  = (const float*)d_in[12];
    const float* ba  = (const float*)d_in[13];
    const float* Wd0 = (const float*)d_in[14];
    const float* bd0 = (const float*)d_in[15];
    const float* Wd  = (const float*)d_in[16];
    const float* bd  = (const float*)d_in[17];
    const float* Wout = (const float*)d_in[18];
    const float* bout = (const float*)d_in[19];
    float* out = (float*)d_out;

    const size_t NH = (size_t)N_NODES * H;
    float* ws = (float*)d_ws;
    float* dinv_r = ws;
    float* dinv_g = dinv_r + N_NODES;
    float* deg    = dinv_g + N_NODES;
    float* hw     = deg + N_NODES;
    float* agg    = hw + NH;
    float* h0     = agg + NH;
    float* h1     = h0 + NH;
    float* xr     = h1 + NH;
    float* xg     = xr + NH;
    float* q4     = xg + NH;
    float* k4     = q4 + 4 * NH;
    float* hcat   = k4 + 4 * NH;
    // total: 3*N + 14*N*H + N*640 floats ~= 58.5 MB

    const int gN   = (N_NODES + 255) / 256;
    const int gE   = (N_EDGES + 255) / 256;
    const int gNH  = (N_NODES * H + 255) / 256;
    const int gE4  = (N_EDGES * (H / 4) + 255) / 256;

    auto layer = [&](const float* hin, int in_dim, const float* W, const float* b,
                     float* hout, const int* edges, const float* dinv) {
        gcn_gemm<<<N_NODES, H, 0, stream>>>(hin, W, hw, in_dim);
        agg_init<<<gNH, 256, 0, stream>>>(hw, dinv, agg);
        agg_edges<<<gE4, 256, 0, stream>>>(edges, hw, dinv, agg);
        bias_relu<<<gNH, 256, 0, stream>>>(agg, b, hout);
    };

    // degrees + norms
    fill_ones<<<gN, 256, 0, stream>>>(deg);
    deg_edges<<<gE, 256, 0, stream>>>(e_rest, deg);
    dinv_kernel<<<gN, 256, 0, stream>>>(deg, dinv_r);
    fill_ones<<<gN, 256, 0, stream>>>(deg);
    deg_edges<<<gE, 256, 0, stream>>>(e_rig, deg);
    dinv_kernel<<<gN, 256, 0, stream>>>(deg, dinv_g);

    // resting encoder
    layer(x_rest, 3, Wr0, br0, h0, e_rest, dinv_r);
    layer(h0, H, Wr, br, h1, e_rest, dinv_r);
    layer(h1, H, Wr + H * H, br + H, xr, e_rest, dinv_r);
    // rigid encoder
    layer(x_rig, 3, Wg0, bg0, h0, e_rig, dinv_g);
    layer(h0, H, Wg, bg, h1, e_rig, dinv_g);
    layer(h1, H, Wg + H * H, bg + H, xg, e_rig, dinv_g);

    // attention projections
    qk_kernel<<<dim3(N_NODES, NHEADS, 2), H, 0, stream>>>(xr, xg, Wa, ba, q4, k4);
    copy_xr<<<gNH, 256, 0, stream>>>(xr, hcat);
    attn_kernel<<<dim3(N_NODES / TQ, NHEADS), 256, 0, stream>>>(q4, k4, xg, hcat);

    // decoder
    decoder<<<N_NODES, H, 0, stream>>>(hcat, Wd0, bd0, Wd, bd, Wout, bout, out);
}

// Round 3
// 2112.807 us; speedup vs baseline: 6.1307x; 2.0100x over previous
//
#include <hip/hip_runtime.h>
#include <math.h>

#define N_NODES 6000
#define N_EDGES 192000
#define H 128
#define NHEADS 4
#define HCAT (H * (NHEADS + 1))   // 640

// attention tile config
#define TQ 48
#define TK 32
#define QSTR 128                  // Qs reads are broadcast -> no pad needed
#define LSTR 132                  // Ks/Vs rows: quad-bank (r + cquad) % 8
#define PSTR 36

// ---------------- CSR build ----------------
__global__ void zero_ints(int* p, int n) {
    int i = blockIdx.x * 256 + threadIdx.x;
    if (i < n) p[i] = 0;
}

__global__ void hist_kernel(const int* __restrict__ edges, int* __restrict__ cnt) {
    int e = blockIdx.x * 256 + threadIdx.x;
    if (e < N_EDGES) atomicAdd(&cnt[edges[N_EDGES + e]], 1);  // target = edges[1]
}

// single block, 1024 threads: exclusive prefix over 6000 counts
__global__ __launch_bounds__(1024)
void scan_kernel(const int* __restrict__ cnt, int* __restrict__ row_start) {
    __shared__ int ps[1024];
    int t = threadIdx.x;
    int base = t * 6;
    int local[6];
    int s = 0;
#pragma unroll
    for (int j = 0; j < 6; ++j) {
        int idx = base + j;
        int v = (idx < N_NODES) ? cnt[idx] : 0;
        local[j] = s;
        s += v;
    }
    ps[t] = s;
    __syncthreads();
    for (int off = 1; off < 1024; off <<= 1) {
        int v = (t >= off) ? ps[t - off] : 0;
        __syncthreads();
        ps[t] += v;
        __syncthreads();
    }
    int ex = (t > 0) ? ps[t - 1] : 0;
#pragma unroll
    for (int j = 0; j < 6; ++j) {
        int idx = base + j;
        if (idx < N_NODES) row_start[idx] = ex + local[j];
    }
    if (t == 1023) row_start[N_NODES] = ps[1023];
}

__global__ void dinv_kernel(const int* __restrict__ cnt, float* __restrict__ dinv) {
    int i = blockIdx.x * 256 + threadIdx.x;
    if (i < N_NODES) dinv[i] = rsqrtf((float)(cnt[i] + 1));  // +1 self loop
}

__global__ void place_kernel(const int* __restrict__ edges, const int* __restrict__ row_start,
                             int* __restrict__ cursor, int* __restrict__ eslot) {
    int e = blockIdx.x * 256 + threadIdx.x;
    if (e < N_EDGES) {
        int t = edges[N_EDGES + e];
        int p = atomicAdd(&cursor[t], 1);
        eslot[row_start[t] + p] = e;
    }
}

// ---------------- GCN pieces ----------------
// hw = h_in @ W, 16 nodes per block. grid 375, block 256.
__global__ __launch_bounds__(256)
void gcn_gemm_b(const float* __restrict__ hin, const float* __restrict__ W,
                float* __restrict__ hw, int in_dim) {
    __shared__ float xs[16 * H];
    int n0 = blockIdx.x * 16;
    int t = threadIdx.x;
    int f = t & (H - 1);
    int g = t >> 7;               // 0/1: nodes g*8..g*8+7
    for (int i = t; i < 16 * H; i += 256) {
        int r = i >> 7, c = i & (H - 1);
        xs[i] = (c < in_dim) ? hin[(size_t)(n0 + r) * in_dim + c] : 0.f;
    }
    __syncthreads();
    float acc[8];
#pragma unroll
    for (int j = 0; j < 8; ++j) acc[j] = 0.f;
    for (int d = 0; d < in_dim; ++d) {
        float w = W[d * H + f];
#pragma unroll
        for (int j = 0; j < 8; ++j) acc[j] += xs[(g * 8 + j) * H + d] * w;
    }
#pragma unroll
    for (int j = 0; j < 8; ++j) hw[(size_t)(n0 + g * 8 + j) * H + f] = acc[j];
}

// gather + self loop + bias + relu. grid 6000, block 128.
__global__ __launch_bounds__(H)
void gather_kernel(const int* __restrict__ edges, const int* __restrict__ eslot,
                   const int* __restrict__ row_start, const float* __restrict__ hw,
                   const float* __restrict__ dinv, const float* __restrict__ b,
                   float* __restrict__ hout) {
    __shared__ int ssrc[128];
    __shared__ float snrm[128];
    int tg = blockIdx.x, f = threadIdx.x;
    int s0 = row_start[tg], s1 = row_start[tg + 1];
    float di = dinv[tg];
    float acc = hw[(size_t)tg * H + f] * di * di;   // self loop
    for (int base = s0; base < s1; base += 128) {
        int cnt = min(128, s1 - base);
        __syncthreads();
        if (f < cnt) {
            int e = eslot[base + f];
            int s = edges[e];
            ssrc[f] = s;
            snrm[f] = dinv[s] * di;
        }
        __syncthreads();
        for (int i = 0; i < cnt; ++i)
            acc += hw[(size_t)ssrc[i] * H + f] * snrm[i];
    }
    float v = acc + b[f];
    hout[(size_t)tg * H + f] = v > 0.f ? v : 0.f;
}

// ---------------- attention q/k projections (16 nodes/block) ----------------
// grid (375, NHEADS, 2): z=0 -> q from xr, z=1 -> k from xg
__global__ __launch_bounds__(256)
void qk_kernel(const float* __restrict__ xr, const float* __restrict__ xg,
               const float* __restrict__ Wa, const float* __restrict__ ba,
               float* __restrict__ q4, float* __restrict__ k4) {
    __shared__ float xs[16 * H];
    int n0 = blockIdx.x * 16, head = blockIdx.y, which = blockIdx.z;
    int t = threadIdx.x;
    int f = t & (H - 1);
    int g = t >> 7;
    const float* src = which ? xg : xr;
    float* dst = which ? k4 : q4;
    for (int i = t; i < 16 * H; i += 256)
        xs[i] = src[(size_t)n0 * H + i];
    __syncthreads();
    const float* W = Wa + (size_t)head * H * H;
    float bias = ba[head * H + f];
    float acc[8];
#pragma unroll
    for (int j = 0; j < 8; ++j) acc[j] = bias;
    for (int d = 0; d < H; ++d) {
        float w = W[d * H + f];
#pragma unroll
        for (int j = 0; j < 8; ++j) acc[j] += xs[(g * 8 + j) * H + d] * w;
    }
#pragma unroll
    for (int j = 0; j < 8; ++j)
        dst[((size_t)head * N_NODES + n0 + g * 8 + j) * H + f] = acc[j];
}

__global__ void copy_xr(const float* __restrict__ xr, float* __restrict__ hcat) {
    int i = blockIdx.x * 256 + threadIdx.x;
    if (i < N_NODES * H) {
        int n = i >> 7, f = i & (H - 1);
        hcat[(size_t)n * HCAT + f] = xr[i];
    }
}

// ---------------- flash attention (fp32, register-tiled) ----------------
// grid (125, NHEADS), block 256. trow=t>>4 (16), tcol=t&15 (16).
// S-phase: rows 3*trow..+2, cols {tcol, tcol+16}  (quad-bank spread: (tcol + d4)%8 covers all 8)
// PV-phase: rows 3*trow..+2, cols {tcol*4..+3, 64+tcol*4..+3}
__global__ __launch_bounds__(256, 2)
void attn_kernel(const float* __restrict__ q4, const float* __restrict__ k4,
                 const float* __restrict__ xg, float* __restrict__ hcat) {
    __shared__ float Qs[TQ * QSTR];
    __shared__ float Ks[TK * LSTR];
    __shared__ float Vs[TK * LSTR];
    __shared__ float Ps[TQ * PSTR];

    const int head = blockIdx.y;
    const int q0 = blockIdx.x * TQ;     // 125*48 == 6000: all q rows valid
    const int t = threadIdx.x;
    const int trow = t >> 4;
    const int tcol = t & 15;
    const float* q = q4 + (size_t)head * N_NODES * H;
    const float* k = k4 + (size_t)head * N_NODES * H;

    for (int i = t; i < TQ * (H / 4); i += 256) {
        int r = i >> 5, c4 = (i & 31) << 2;
        *(float4*)&Qs[r * QSTR + c4] = *(const float4*)&q[(size_t)(q0 + r) * H + c4];
    }

    float O[3][8];
    float m[3], l[3];
#pragma unroll
    for (int j = 0; j < 3; ++j) {
        m[j] = -1e30f; l[j] = 0.f;
#pragma unroll
        for (int u = 0; u < 8; ++u) O[j][u] = 0.f;
    }

    for (int k0 = 0; k0 < N_NODES; k0 += TK) {
        __syncthreads();   // prev PV done reading Ks/Vs
        for (int i = t; i < TK * (H / 4); i += 256) {
            int r = i >> 5, c4 = (i & 31) << 2;
            bool ok = (k0 + r) < N_NODES;
            float4 kv = ok ? *(const float4*)&k[(size_t)(k0 + r) * H + c4] : float4{0.f, 0.f, 0.f, 0.f};
            float4 vv = ok ? *(const float4*)&xg[(size_t)(k0 + r) * H + c4] : float4{0.f, 0.f, 0.f, 0.f};
            *(float4*)&Ks[r * LSTR + c4] = kv;
            *(float4*)&Vs[r * LSTR + c4] = vv;
        }
        __syncthreads();

        // ---- S = Q K^T: cols tcol and tcol+16 ----
        float s0[3] = {0.f, 0.f, 0.f};
        float s1[3] = {0.f, 0.f, 0.f};
#pragma unroll 4
        for (int d4 = 0; d4 < H / 4; ++d4) {
            float4 kf0 = *(float4*)&Ks[tcol * LSTR + d4 * 4];
            float4 kf1 = *(float4*)&Ks[(tcol + 16) * LSTR + d4 * 4];
#pragma unroll
            for (int j = 0; j < 3; ++j) {
                float4 qf = *(float4*)&Qs[(trow * 3 + j) * QSTR + d4 * 4];
                s0[j] += qf.x * kf0.x + qf.y * kf0.y + qf.z * kf0.z + qf.w * kf0.w;
                s1[j] += qf.x * kf1.x + qf.y * kf1.y + qf.z * kf1.z + qf.w * kf1.w;
            }
        }

        // ---- online softmax (16-lane shfl butterflies) ----
        bool v0 = (k0 + tcol) < N_NODES;
        bool v1 = (k0 + tcol + 16) < N_NODES;
        float alpha[3];
#pragma unroll
        for (int j = 0; j < 3; ++j) {
            float a0 = v0 ? s0[j] : -1e30f;
            float a1 = v1 ? s1[j] : -1e30f;
            float mx = fmaxf(a0, a1);
            mx = fmaxf(mx, __shfl_xor(mx, 1));
            mx = fmaxf(mx, __shfl_xor(mx, 2));
            mx = fmaxf(mx, __shfl_xor(mx, 4));
            mx = fmaxf(mx, __shfl_xor(mx, 8));
            float mn = fmaxf(m[j], mx);
            alpha[j] = expf(m[j] - mn);
            float p0 = expf(a0 - mn);
            float p1 = expf(a1 - mn);
            float ps = p0 + p1;
            ps += __shfl_xor(ps, 1);
            ps += __shfl_xor(ps, 2);
            ps += __shfl_xor(ps, 4);
            ps += __shfl_xor(ps, 8);
            l[j] = l[j] * alpha[j] + ps;
            m[j] = mn;
            Ps[(trow * 3 + j) * PSTR + tcol] = p0;
            Ps[(trow * 3 + j) * PSTR + tcol + 16] = p1;
        }
        __syncthreads();

        // ---- O = O*alpha + P V: cols tcol*4..+3 and 64+tcol*4..+3 ----
#pragma unroll
        for (int j = 0; j < 3; ++j)
#pragma unroll
            for (int u = 0; u < 8; ++u) O[j][u] *= alpha[j];

#pragma unroll 2
        for (int k4i = 0; k4i < TK / 4; ++k4i) {
            float4 pf[3];
#pragma unroll
            for (int j = 0; j < 3; ++j)
                pf[j] = *(float4*)&Ps[(trow * 3 + j) * PSTR + k4i * 4];
#pragma unroll
            for (int kk = 0; kk < 4; ++kk) {
                float4 va = *(float4*)&Vs[(k4i * 4 + kk) * LSTR + tcol * 4];
                float4 vb = *(float4*)&Vs[(k4i * 4 + kk) * LSTR + 64 + tcol * 4];
#pragma unroll
                for (int j = 0; j < 3; ++j) {
                    float p = ((const float*)&pf[j])[kk];
                    O[j][0] += p * va.x; O[j][1] += p * va.y;
                    O[j][2] += p * va.z; O[j][3] += p * va.w;
                    O[j][4] += p * vb.x; O[j][5] += p * vb.y;
                    O[j][6] += p * vb.z; O[j][7] += p * vb.w;
                }
            }
        }
    }

    // ---- epilogue ----
#pragma unroll
    for (int j = 0; j < 3; ++j) {
        float inv = 1.f / l[j];
        int n = q0 + trow * 3 + j;
        float* dst = &hcat[(size_t)n * HCAT + H + head * H];
        float4 oa = {O[j][0] * inv, O[j][1] * inv, O[j][2] * inv, O[j][3] * inv};
        float4 ob = {O[j][4] * inv, O[j][5] * inv, O[j][6] * inv, O[j][7] * inv};
        *(float4*)(dst + tcol * 4) = oa;
        *(float4*)(dst + 64 + tcol * 4) = ob;
    }
}

// ---------------- fused decoder MLP (8 nodes/block) ----------------
// grid 750, block 256
__global__ __launch_bounds__(256)
void decoder(const float* __restrict__ hcat,
             const float* __restrict__ Wd0, const float* __restrict__ bd0,
             const float* __restrict__ Wd, const float* __restrict__ bd,
             const float* __restrict__ Wout, const float* __restrict__ bout,
             float* __restrict__ out) {
    __shared__ float s0[8 * HCAT];   // 20 KB
    __shared__ float s1[8 * H];
    __shared__ float s2[8 * H];
    int n0 = blockIdx.x * 8;
    int t = threadIdx.x;
    int f = t & (H - 1);
    int g = t >> 7;                  // nodes g*4..g*4+3
    for (int i = t; i < 8 * HCAT; i += 256)
        s0[i] = hcat[(size_t)n0 * HCAT + i];
    __syncthreads();

    float acc[4];
#pragma unroll
    for (int j = 0; j < 4; ++j) acc[j] = bd0[f];
    for (int d = 0; d < HCAT; ++d) {
        float w = Wd0[d * H + f];
#pragma unroll
        for (int j = 0; j < 4; ++j) acc[j] += s0[(g * 4 + j) * HCAT + d] * w;
    }
#pragma unroll
    for (int j = 0; j < 4; ++j) s1[(g * 4 + j) * H + f] = fmaxf(acc[j], 0.f);
    __syncthreads();

#pragma unroll
    for (int j = 0; j < 4; ++j) acc[j] = bd[f];
    for (int d = 0; d < H; ++d) {
        float w = Wd[d * H + f];
#pragma unroll
        for (int j = 0; j < 4; ++j) acc[j] += s1[(g * 4 + j) * H + d] * w;
    }
#pragma unroll
    for (int j = 0; j < 4; ++j) s2[(g * 4 + j) * H + f] = fmaxf(acc[j], 0.f);
    __syncthreads();

#pragma unroll
    for (int j = 0; j < 4; ++j) acc[j] = bd[H + f];
    for (int d = 0; d < H; ++d) {
        float w = Wd[H * H + d * H + f];
#pragma unroll
        for (int j = 0; j < 4; ++j) acc[j] += s2[(g * 4 + j) * H + d] * w;
    }
    __syncthreads();
#pragma unroll
    for (int j = 0; j < 4; ++j) s1[(g * 4 + j) * H + f] = fmaxf(acc[j], 0.f);
    __syncthreads();

    // out: 8 nodes x 3 = 24 outputs, threads 0..23
    if (t < 24) {
        int n = t / 3, c = t % 3;
        float o = bout[c];
        for (int d = 0; d < H; ++d) o += s1[n * H + d] * Wout[d * 3 + c];
        out[(size_t)(n0 + n) * 3 + c] = o;
    }
}

// ---------------- launch ----------------
extern "C" void kernel_launch(void* const* d_in, const int* in_sizes, int n_in,
                              void* d_out, int out_size, void* d_ws, size_t ws_size,
                              hipStream_t stream) {
    const float* x_rest = (const float*)d_in[0];
    const float* x_rig  = (const float*)d_in[1];
    const int*   e_rest = (const int*)d_in[2];
    const int*   e_rig  = (const int*)d_in[3];
    const float* Wr0 = (const float*)d_in[4];
    const float* br0 = (const float*)d_in[5];
    const float* Wr  = (const float*)d_in[6];
    const float* br  = (const float*)d_in[7];
    const float* Wg0 = (const float*)d_in[8];
    const float* bg0 = (const float*)d_in[9];
    const float* Wg  = (const float*)d_in[10];
    const float* bg  = (const float*)d_in[11];
    const float* Wa  = (const float*)d_in[12];
    const float* ba  = (const float*)d_in[13];
    const float* Wd0 = (const float*)d_in[14];
    const float* bd0 = (const float*)d_in[15];
    const float* Wd  = (const float*)d_in[16];
    const float* bd  = (const float*)d_in[17];
    const float* Wout = (const float*)d_in[18];
    const float* bout = (const float*)d_in[19];
    float* out = (float*)d_out;

    const size_t NH = (size_t)N_NODES * H;
    float* ws = (float*)d_ws;
    float* dinv_r = ws;
    float* dinv_g = dinv_r + N_NODES;
    float* hw     = dinv_g + N_NODES;
    float* h0     = hw + NH;
    float* h1     = h0 + NH;
    float* xr     = h1 + NH;
    float* xg     = xr + NH;
    float* q4     = xg + NH;
    float* k4     = q4 + 4 * NH;
    float* hcat   = k4 + 4 * NH;
    int*   ibase  = (int*)(hcat + (size_t)N_NODES * HCAT);
    int* cnt_r    = ibase;
    int* cnt_g    = cnt_r + N_NODES;
    int* cur_r    = cnt_g + N_NODES;
    int* cur_g    = cur_r + N_NODES;
    int* rs_r     = cur_g + N_NODES;            // N+1
    int* rs_g     = rs_r + N_NODES + 1;         // N+1
    int* eslot_r  = rs_g + N_NODES + 1;
    int* eslot_g  = eslot_r + N_EDGES;
    // total ~55.4 MB floats + ~1.7 MB ints

    const int gN  = (N_NODES + 255) / 256;
    const int gE  = (N_EDGES + 255) / 256;
    const int gNH = (N_NODES * H + 255) / 256;

    // ---- CSR build (both graphs) ----
    zero_ints<<<(4 * N_NODES + 255) / 256, 256, 0, stream>>>(cnt_r, 4 * N_NODES); // cnt_r,cnt_g,cur_r,cur_g
    hist_kernel<<<gE, 256, 0, stream>>>(e_rest, cnt_r);
    hist_kernel<<<gE, 256, 0, stream>>>(e_rig, cnt_g);
    scan_kernel<<<1, 1024, 0, stream>>>(cnt_r, rs_r);
    scan_kernel<<<1, 1024, 0, stream>>>(cnt_g, rs_g);
    dinv_kernel<<<gN, 256, 0, stream>>>(cnt_r, dinv_r);
    dinv_kernel<<<gN, 256, 0, stream>>>(cnt_g, dinv_g);
    place_kernel<<<gE, 256, 0, stream>>>(e_rest, rs_r, cur_r, eslot_r);
    place_kernel<<<gE, 256, 0, stream>>>(e_rig, rs_g, cur_g, eslot_g);

    auto layer = [&](const float* hin, int in_dim, const float* W, const float* b,
                     float* hout, const int* edges, const int* eslot, const int* rs,
                     const float* dinv) {
        gcn_gemm_b<<<N_NODES / 16, 256, 0, stream>>>(hin, W, hw, in_dim);
        gather_kernel<<<N_NODES, H, 0, stream>>>(edges, eslot, rs, hw, dinv, b, hout);
    };

    // resting encoder
    layer(x_rest, 3, Wr0, br0, h0, e_rest, eslot_r, rs_r, dinv_r);
    layer(h0, H, Wr, br, h1, e_rest, eslot_r, rs_r, dinv_r);
    layer(h1, H, Wr + H * H, br + H, xr, e_rest, eslot_r, rs_r, dinv_r);
    // rigid encoder
    layer(x_rig, 3, Wg0, bg0, h0, e_rig, eslot_g, rs_g, dinv_g);
    layer(h0, H, Wg, bg, h1, e_rig, eslot_g, rs_g, dinv_g);
    layer(h1, H, Wg + H * H, bg + H, xg, e_rig, eslot_g, rs_g, dinv_g);

    // attention projections
    qk_kernel<<<dim3(N_NODES / 16, NHEADS, 2), 256, 0, stream>>>(xr, xg, Wa, ba, q4, k4);
    copy_xr<<<gNH, 256, 0, stream>>>(xr, hcat);
    attn_kernel<<<dim3(N_NODES / TQ, NHEADS), 256, 0, stream>>>(q4, k4, xg, hcat);

    // decoder
    decoder<<<N_NODES / 8, 256, 0, stream>>>(hcat, Wd0, bd0, Wd, bd, Wout, bout, out);
}

// Round 4
// 875.459 us; speedup vs baseline: 14.7956x; 2.4134x over previous
//
#include <hip/hip_runtime.h>
#include <math.h>

#define N_NODES 6000
#define N_EDGES 192000
#define H 128
#define NHEADS 4
#define HCAT 640
#define NPAD 6016       // K arrays padded to 6016 rows
#define NTILES 188      // ceil(6000/32)

typedef unsigned short ushort_t;
typedef __attribute__((ext_vector_type(8))) short short8;
typedef __attribute__((ext_vector_type(16))) float f32x16;

__device__ __forceinline__ void bf16split(float x, ushort_t& hi, ushort_t& lo) {
    unsigned ub = __float_as_uint(x);
    unsigned hb = ub & 0xffff0000u;
    float l = x - __uint_as_float(hb);
    hi = (ushort_t)(hb >> 16);
    lo = (ushort_t)(__float_as_uint(l) >> 16);
}

__device__ __forceinline__ void gll16(const ushort_t* g, ushort_t* l) {
    __builtin_amdgcn_global_load_lds((const __attribute__((address_space(1))) void*)g,
                                     (__attribute__((address_space(3))) void*)l, 16, 0, 0);
}

// ---------------- CSR build ----------------
__global__ void zero_ints(int* p, int n) {
    int i = blockIdx.x * 256 + threadIdx.x;
    if (i < n) p[i] = 0;
}

__global__ void hist_kernel(const int* __restrict__ edges, int* __restrict__ cnt) {
    int e = blockIdx.x * 256 + threadIdx.x;
    if (e < N_EDGES) atomicAdd(&cnt[edges[N_EDGES + e]], 1);  // target = edges[1]
}

__global__ __launch_bounds__(1024)
void scan_kernel(const int* __restrict__ cnt, int* __restrict__ row_start) {
    __shared__ int ps[1024];
    int t = threadIdx.x;
    int base = t * 6;
    int local[6];
    int s = 0;
#pragma unroll
    for (int j = 0; j < 6; ++j) {
        int idx = base + j;
        int v = (idx < N_NODES) ? cnt[idx] : 0;
        local[j] = s;
        s += v;
    }
    ps[t] = s;
    __syncthreads();
    for (int off = 1; off < 1024; off <<= 1) {
        int v = (t >= off) ? ps[t - off] : 0;
        __syncthreads();
        ps[t] += v;
        __syncthreads();
    }
    int ex = (t > 0) ? ps[t - 1] : 0;
#pragma unroll
    for (int j = 0; j < 6; ++j) {
        int idx = base + j;
        if (idx < N_NODES) row_start[idx] = ex + local[j];
    }
    if (t == 1023) row_start[N_NODES] = ps[1023];
}

__global__ void dinv_kernel(const int* __restrict__ cnt, float* __restrict__ dinv) {
    int i = blockIdx.x * 256 + threadIdx.x;
    if (i < N_NODES) dinv[i] = rsqrtf((float)(cnt[i] + 1));
}

__global__ void place_kernel(const int* __restrict__ edges, const int* __restrict__ row_start,
                             int* __restrict__ cursor, int* __restrict__ eslot) {
    int e = blockIdx.x * 256 + threadIdx.x;
    if (e < N_EDGES) {
        int t = edges[N_EDGES + e];
        int p = atomicAdd(&cursor[t], 1);
        eslot[row_start[t] + p] = e;
    }
}

// ---------------- GCN pieces ----------------
__global__ __launch_bounds__(256)
void gcn_gemm_b(const float* __restrict__ hin, const float* __restrict__ W,
                float* __restrict__ hw, int in_dim) {
    __shared__ float xs[16 * H];
    int n0 = blockIdx.x * 16;
    int t = threadIdx.x;
    int f = t & (H - 1);
    int g = t >> 7;
    for (int i = t; i < 16 * H; i += 256) {
        int r = i >> 7, c = i & (H - 1);
        xs[i] = (c < in_dim) ? hin[(size_t)(n0 + r) * in_dim + c] : 0.f;
    }
    __syncthreads();
    float acc[8];
#pragma unroll
    for (int j = 0; j < 8; ++j) acc[j] = 0.f;
    for (int d = 0; d < in_dim; ++d) {
        float w = W[d * H + f];
#pragma unroll
        for (int j = 0; j < 8; ++j) acc[j] += xs[(g * 8 + j) * H + d] * w;
    }
#pragma unroll
    for (int j = 0; j < 8; ++j) hw[(size_t)(n0 + g * 8 + j) * H + f] = acc[j];
}

__global__ __launch_bounds__(H)
void gather_kernel(const int* __restrict__ edges, const int* __restrict__ eslot,
                   const int* __restrict__ row_start, const float* __restrict__ hw,
                   const float* __restrict__ dinv, const float* __restrict__ b,
                   float* __restrict__ hout) {
    __shared__ int ssrc[128];
    __shared__ float snrm[128];
    int tg = blockIdx.x, f = threadIdx.x;
    int s0 = row_start[tg], s1 = row_start[tg + 1];
    float di = dinv[tg];
    float acc = hw[(size_t)tg * H + f] * di * di;
    for (int base = s0; base < s1; base += 128) {
        int cnt = min(128, s1 - base);
        __syncthreads();
        if (f < cnt) {
            int e = eslot[base + f];
            int s = edges[e];
            ssrc[f] = s;
            snrm[f] = dinv[s] * di;
        }
        __syncthreads();
        for (int i = 0; i < cnt; ++i)
            acc += hw[(size_t)ssrc[i] * H + f] * snrm[i];
    }
    float v = acc + b[f];
    hout[(size_t)tg * H + f] = v > 0.f ? v : 0.f;
}

// ---------------- q/k projections -> bf16 hi/lo (K swizzled) ----------------
// grid (375, NHEADS, 2): z=0 -> Q from xr, z=1 -> K from xg
__global__ __launch_bounds__(256)
void qk_kernel(const float* __restrict__ xr, const float* __restrict__ xg,
               const float* __restrict__ Wa, const float* __restrict__ ba,
               ushort_t* __restrict__ Qh, ushort_t* __restrict__ Ql,
               ushort_t* __restrict__ Khs, ushort_t* __restrict__ Kls) {
    __shared__ float xs[16 * H];
    int n0 = blockIdx.x * 16, head = blockIdx.y, which = blockIdx.z;
    int t = threadIdx.x;
    int f = t & (H - 1);
    int g = t >> 7;
    const float* src = which ? xg : xr;
    for (int i = t; i < 16 * H; i += 256)
        xs[i] = src[(size_t)n0 * H + i];
    __syncthreads();
    const float* W = Wa + (size_t)head * H * H;
    float bias = ba[head * H + f];
    float acc[8];
#pragma unroll
    for (int j = 0; j < 8; ++j) acc[j] = bias;
    for (int d = 0; d < H; ++d) {
        float w = W[d * H + f];
#pragma unroll
        for (int j = 0; j < 8; ++j) acc[j] += xs[(g * 8 + j) * H + d] * w;
    }
#pragma unroll
    for (int j = 0; j < 8; ++j) {
        int n = n0 + g * 8 + j;
        ushort_t hi, lo;
        bf16split(acc[j], hi, lo);
        if (which == 0) {
            size_t idx = ((size_t)(head * N_NODES + n) << 7) + f;
            Qh[idx] = hi; Ql[idx] = lo;
        } else {
            int pos = (((f >> 3) ^ (n & 15)) << 3) + (f & 7);
            size_t idx = ((size_t)(head * NPAD + n) << 7) + pos;
            Khs[idx] = hi; Kls[idx] = lo;
        }
    }
}

__global__ void zero_pad_k(ushort_t* __restrict__ Khs, ushort_t* __restrict__ Kls) {
    int i = blockIdx.x * 256 + threadIdx.x;
    if (i < NHEADS * 16 * H) {
        int head = i / (16 * H);
        int rest = i - head * 16 * H;
        int n = N_NODES + (rest >> 7);
        int f = rest & 127;
        size_t idx = ((size_t)(head * NPAD + n) << 7) + f;
        Khs[idx] = 0; Kls[idx] = 0;
    }
}

// ---------------- V transpose -> tiled swizzled bf16 hi/lo ----------------
// grid 188, block 128. Output layout: [tile][d][ ((kk>>3)^(d&3))*8 + (kk&7) ]
__global__ __launch_bounds__(128)
void cvt_vt(const float* __restrict__ xg, ushort_t* __restrict__ Vth, ushort_t* __restrict__ Vtl) {
    __shared__ float vs[32][129];
    int t0 = blockIdx.x;
    int t = threadIdx.x;
    for (int c = t; c < 32 * 32; c += 128) {
        int row = c >> 5, col4 = (c & 31) << 2;
        int n = t0 * 32 + row;
        float4 v = (n < N_NODES) ? *(const float4*)&xg[(size_t)n * H + col4]
                                 : float4{0.f, 0.f, 0.f, 0.f};
        vs[row][col4 + 0] = v.x; vs[row][col4 + 1] = v.y;
        vs[row][col4 + 2] = v.z; vs[row][col4 + 3] = v.w;
    }
    __syncthreads();
    int d = t;
    size_t base = ((size_t)t0 * H + d) * 32;
#pragma unroll
    for (int oc = 0; oc < 4; ++oc) {
        int cc = oc ^ (d & 3);
        unsigned uh[4], ul[4];
#pragma unroll
        for (int j = 0; j < 4; ++j) {
            ushort_t h0, l0, h1, l1;
            bf16split(vs[cc * 8 + 2 * j][d], h0, l0);
            bf16split(vs[cc * 8 + 2 * j + 1][d], h1, l1);
            uh[j] = (unsigned)h0 | ((unsigned)h1 << 16);
            ul[j] = (unsigned)l0 | ((unsigned)l1 << 16);
        }
        *(uint4*)&Vth[base + oc * 8] = make_uint4(uh[0], uh[1], uh[2], uh[3]);
        *(uint4*)&Vtl[base + oc * 8] = make_uint4(ul[0], ul[1], ul[2], ul[3]);
    }
}

__global__ void copy_xr(const float* __restrict__ xr, float* __restrict__ hcat) {
    int i = blockIdx.x * 256 + threadIdx.x;
    if (i < N_NODES * H) {
        int n = i >> 7, f = i & (H - 1);
        hcat[(size_t)n * HCAT + f] = xr[i];
    }
}

// ---------------- MFMA flash attention (bf16x2 emulated fp32) ----------------
// grid (94, 4), block 128 (2 waves). Wave w owns q rows q0+w*32..+31.
// S^T = K*Q^T via mfma_32x32x16 (C: col=lane&31=q, row=(reg&3)+8*(reg>>2)+4*half=k).
// P converted to A-operand via one cross-half shfl per reg; V from transposed tiles.
__global__ __launch_bounds__(128, 1)
void attn_mfma(const ushort_t* __restrict__ Qh, const ushort_t* __restrict__ Ql,
               const ushort_t* __restrict__ Khs, const ushort_t* __restrict__ Kls,
               const ushort_t* __restrict__ Vth, const ushort_t* __restrict__ Vtl,
               float* __restrict__ hcat) {
    __shared__ ushort_t lds[2][4][4096];   // [buf][Kh,Kl,Vh,Vl][8KB]
    const int head = blockIdx.y;
    const int t = threadIdx.x;
    const int w = t >> 6;
    const int lane = t & 63;
    const int r = lane & 31;
    const int h = lane >> 5;
    const int q0w = blockIdx.x * 64 + w * 32;

    // Q B-fragments in registers: rows q0w+r, dims 16s+8h+j
    int qr = q0w + r; if (qr > N_NODES - 1) qr = N_NODES - 1;
    const size_t qbase = ((size_t)(head * N_NODES + qr)) << 7;
    short8 qfh[8], qfl[8];
#pragma unroll
    for (int s = 0; s < 8; ++s) {
        qfh[s] = *(const short8*)&Qh[qbase + 16 * s + 8 * h];
        qfl[s] = *(const short8*)&Ql[qbase + 16 * s + 8 * h];
    }

    f32x16 O[4];
#pragma unroll
    for (int sub = 0; sub < 4; ++sub)
#pragma unroll
        for (int i = 0; i < 16; ++i) O[sub][i] = 0.f;
    float mrun = -1e30f, lrun = 0.f;

    const ushort_t* gK = w ? Kls : Khs;
    const ushort_t* gV = w ? Vtl : Vth;
    const size_t kbase = (size_t)head * NPAD * H;

    // prologue: stage tile 0 into buf 0
    {
        ushort_t* lK = &lds[0][w][0];
        ushort_t* lV = &lds[0][2 + w][0];
        const ushort_t* sK = &gK[kbase];
        const ushort_t* sV = &gV[0];
#pragma unroll
        for (int i = 0; i < 8; ++i) {
            gll16(sK + i * 512 + lane * 8, lK + i * 512 + lane * 8);
            gll16(sV + i * 512 + lane * 8, lV + i * 512 + lane * 8);
        }
    }

    for (int it = 0; it < NTILES; ++it) {
        __syncthreads();   // drains vmcnt: buf[it&1] ready; prior reads of buf[(it+1)&1] done
        {
            int nt = it + 1; if (nt >= NTILES) nt = 0;
            int nb = (it + 1) & 1;
            ushort_t* lK = &lds[nb][w][0];
            ushort_t* lV = &lds[nb][2 + w][0];
            const ushort_t* sK = &gK[kbase + (size_t)nt * 32 * H];
            const ushort_t* sV = &gV[(size_t)nt * 4096];
#pragma unroll
            for (int i = 0; i < 8; ++i) {
                gll16(sK + i * 512 + lane * 8, lK + i * 512 + lane * 8);
                gll16(sV + i * 512 + lane * 8, lV + i * 512 + lane * 8);
            }
        }
        const int b = it & 1;
        const ushort_t* lKh = &lds[b][0][0];
        const ushort_t* lKl = &lds[b][1][0];
        const ushort_t* lVh = &lds[b][2][0];
        const ushort_t* lVl = &lds[b][3][0];

        // ---- S^T = (Kh+Kl)(Qh+Ql)^T, dropping lo*lo ----
        f32x16 acc;
#pragma unroll
        for (int i = 0; i < 16; ++i) acc[i] = 0.f;
        const int krow = r * H;
#pragma unroll
        for (int s = 0; s < 8; ++s) {
            int cc = ((2 * s + h) ^ (r & 15)) << 3;
            short8 ah = *(const short8*)&lKh[krow + cc];
            short8 al = *(const short8*)&lKl[krow + cc];
            acc = __builtin_amdgcn_mfma_f32_32x32x16_bf16(ah, qfh[s], acc, 0, 0, 0);
            acc = __builtin_amdgcn_mfma_f32_32x32x16_bf16(ah, qfl[s], acc, 0, 0, 0);
            acc = __builtin_amdgcn_mfma_f32_32x32x16_bf16(al, qfh[s], acc, 0, 0, 0);
        }

        // ---- online softmax over k (rows of S^T) for this lane's q (col) ----
        float sv[16];
#pragma unroll
        for (int i = 0; i < 16; ++i) sv[i] = acc[i];
        int klim = N_NODES - (it << 5);
        if (klim < 32) {
#pragma unroll
            for (int i = 0; i < 16; ++i) {
                int row = (i & 3) + 8 * (i >> 2) + 4 * h;
                if (row >= klim) sv[i] = -1e30f;
            }
        }
        float tmax = sv[0];
#pragma unroll
        for (int i = 1; i < 16; ++i) tmax = fmaxf(tmax, sv[i]);
        tmax = fmaxf(tmax, __shfl_xor(tmax, 32));
        float mnew = fmaxf(mrun, tmax);
        float alpha = __expf(mrun - mnew);
        float p[16];
        float psum = 0.f;
#pragma unroll
        for (int i = 0; i < 16; ++i) { p[i] = __expf(sv[i] - mnew); psum += p[i]; }
        psum += __shfl_xor(psum, 32);
        lrun = lrun * alpha + psum;
        mrun = mnew;

        // rescale O: alpha gathered per C-row q
#pragma unroll
        for (int i = 0; i < 16; ++i) {
            int rowq = (i & 3) + 8 * (i >> 2) + 4 * h;
            float a = __shfl(alpha, rowq);
#pragma unroll
            for (int sub = 0; sub < 4; ++sub) O[sub][i] *= a;
        }

        // ---- P (C-layout, transposed) -> A-operand frags via cross-half shfl ----
        float pr[16];
#pragma unroll
        for (int i = 0; i < 16; ++i) pr[i] = __shfl_xor(p[i], 32);
        short8 aPh[2], aPl[2];
#pragma unroll
        for (int s2 = 0; s2 < 2; ++s2) {
#pragma unroll
            for (int j = 0; j < 8; ++j) {
                int c = j & 3;
                float v;
                if (j < 4) v = (h == 0) ? p[c + 8 * s2] : pr[c + 8 * s2 + 4];
                else       v = (h == 1) ? p[c + 8 * s2 + 4] : pr[c + 8 * s2];
                unsigned ub = __float_as_uint(v);
                unsigned hb = ub & 0xffff0000u;
                float lo = v - __uint_as_float(hb);
                aPh[s2][j] = (short)(hb >> 16);
                aPl[s2][j] = (short)(__float_as_uint(lo) >> 16);
            }
        }

        // ---- O += (Ph+Pl)(Vh+Vl), dropping lo*lo ----
#pragma unroll
        for (int sub = 0; sub < 4; ++sub) {
            const int vrow = (32 * sub + r) * 32;
#pragma unroll
            for (int s2 = 0; s2 < 2; ++s2) {
                int cc = (((2 * s2 + h) ^ (r & 3)) << 3);
                short8 bh = *(const short8*)&lVh[vrow + cc];
                short8 bl = *(const short8*)&lVl[vrow + cc];
                O[sub] = __builtin_amdgcn_mfma_f32_32x32x16_bf16(aPh[s2], bh, O[sub], 0, 0, 0);
                O[sub] = __builtin_amdgcn_mfma_f32_32x32x16_bf16(aPh[s2], bl, O[sub], 0, 0, 0);
                O[sub] = __builtin_amdgcn_mfma_f32_32x32x16_bf16(aPl[s2], bh, O[sub], 0, 0, 0);
            }
        }
    }

    // ---- epilogue ----
    float linv = 1.0f / lrun;
#pragma unroll
    for (int i = 0; i < 16; ++i) {
        int rowq = (i & 3) + 8 * (i >> 2) + 4 * h;
        float li = __shfl(linv, rowq);
        int qg = q0w + rowq;
        if (qg < N_NODES) {
            float* dst = &hcat[(size_t)qg * HCAT + H + head * H + r];
#pragma unroll
            for (int sub = 0; sub < 4; ++sub) dst[32 * sub] = O[sub][i] * li;
        }
    }
}

// ---------------- fused decoder MLP (8 nodes/block) ----------------
__global__ __launch_bounds__(256)
void decoder(const float* __restrict__ hcat,
             const float* __restrict__ Wd0, const float* __restrict__ bd0,
             const float* __restrict__ Wd, const float* __restrict__ bd,
             const float* __restrict__ Wout, const float* __restrict__ bout,
             float* __restrict__ out) {
    __shared__ float s0[8 * HCAT];
    __shared__ float s1[8 * H];
    __shared__ float s2[8 * H];
    int n0 = blockIdx.x * 8;
    int t = threadIdx.x;
    int f = t & (H - 1);
    int g = t >> 7;
    for (int i = t; i < 8 * HCAT; i += 256)
        s0[i] = hcat[(size_t)n0 * HCAT + i];
    __syncthreads();

    float acc[4];
#pragma unroll
    for (int j = 0; j < 4; ++j) acc[j] = bd0[f];
    for (int d = 0; d < HCAT; ++d) {
        float w = Wd0[d * H + f];
#pragma unroll
        for (int j = 0; j < 4; ++j) acc[j] += s0[(g * 4 + j) * HCAT + d] * w;
    }
#pragma unroll
    for (int j = 0; j < 4; ++j) s1[(g * 4 + j) * H + f] = fmaxf(acc[j], 0.f);
    __syncthreads();

#pragma unroll
    for (int j = 0; j < 4; ++j) acc[j] = bd[f];
    for (int d = 0; d < H; ++d) {
        float w = Wd[d * H + f];
#pragma unroll
        for (int j = 0; j < 4; ++j) acc[j] += s1[(g * 4 + j) * H + d] * w;
    }
#pragma unroll
    for (int j = 0; j < 4; ++j) s2[(g * 4 + j) * H + f] = fmaxf(acc[j], 0.f);
    __syncthreads();

#pragma unroll
    for (int j = 0; j < 4; ++j) acc[j] = bd[H + f];
    for (int d = 0; d < H; ++d) {
        float w = Wd[H * H + d * H + f];
#pragma unroll
        for (int j = 0; j < 4; ++j) acc[j] += s2[(g * 4 + j) * H + d] * w;
    }
    __syncthreads();
#pragma unroll
    for (int j = 0; j < 4; ++j) s1[(g * 4 + j) * H + f] = fmaxf(acc[j], 0.f);
    __syncthreads();

    if (t < 24) {
        int n = t / 3, c = t % 3;
        float o = bout[c];
        for (int d = 0; d < H; ++d) o += s1[n * H + d] * Wout[d * 3 + c];
        out[(size_t)(n0 + n) * 3 + c] = o;
    }
}

// ---------------- launch ----------------
extern "C" void kernel_launch(void* const* d_in, const int* in_sizes, int n_in,
                              void* d_out, int out_size, void* d_ws, size_t ws_size,
                              hipStream_t stream) {
    const float* x_rest = (const float*)d_in[0];
    const float* x_rig  = (const float*)d_in[1];
    const int*   e_rest = (const int*)d_in[2];
    const int*   e_rig  = (const int*)d_in[3];
    const float* Wr0 = (const float*)d_in[4];
    const float* br0 = (const float*)d_in[5];
    const float* Wr  = (const float*)d_in[6];
    const float* br  = (const float*)d_in[7];
    const float* Wg0 = (const float*)d_in[8];
    const float* bg0 = (const float*)d_in[9];
    const float* Wg  = (const float*)d_in[10];
    const float* bg  = (const float*)d_in[11];
    const float* Wa  = (const float*)d_in[12];
    const float* ba  = (const float*)d_in[13];
    const float* Wd0 = (const float*)d_in[14];
    const float* bd0 = (const float*)d_in[15];
    const float* Wd  = (const float*)d_in[16];
    const float* bd  = (const float*)d_in[17];
    const float* Wout = (const float*)d_in[18];
    const float* bout = (const float*)d_in[19];
    float* out = (float*)d_out;

    const size_t NH = (size_t)N_NODES * H;       // 768000
    float* ws = (float*)d_ws;
    float* dinv_r = ws;
    float* dinv_g = dinv_r + N_NODES;
    float* hw     = dinv_g + N_NODES;
    float* h0     = hw + NH;
    float* h1     = h0 + NH;
    float* xr     = h1 + NH;
    float* xg     = xr + NH;
    float* hcat   = xg + NH;                     // 3,840,000 floats
    ushort_t* Qh  = (ushort_t*)(hcat + (size_t)N_NODES * HCAT);
    ushort_t* Ql  = Qh + (size_t)NHEADS * N_NODES * H;       // 3,072,000 each
    ushort_t* Khs = Ql + (size_t)NHEADS * N_NODES * H;
    ushort_t* Kls = Khs + (size_t)NHEADS * NPAD * H;         // 3,080,192 each
    ushort_t* Vth = Kls + (size_t)NHEADS * NPAD * H;
    ushort_t* Vtl = Vth + (size_t)NTILES * H * 32;           // 770,048 each
    int* ib       = (int*)(Vtl + (size_t)NTILES * H * 32);
    int* cnt_r    = ib;
    int* cnt_g    = cnt_r + N_NODES;
    int* cur_r    = cnt_g + N_NODES;
    int* cur_g    = cur_r + N_NODES;
    int* rs_r     = cur_g + N_NODES;
    int* rs_g     = rs_r + N_NODES + 1;
    int* eslot_r  = rs_g + N_NODES + 1;
    int* eslot_g  = eslot_r + N_EDGES;
    // total ~60.2 MB

    const int gN  = (N_NODES + 255) / 256;
    const int gE  = (N_EDGES + 255) / 256;
    const int gNH = (N_NODES * H + 255) / 256;

    // ---- CSR build ----
    zero_ints<<<(4 * N_NODES + 255) / 256, 256, 0, stream>>>(cnt_r, 4 * N_NODES);
    hist_kernel<<<gE, 256, 0, stream>>>(e_rest, cnt_r);
    hist_kernel<<<gE, 256, 0, stream>>>(e_rig, cnt_g);
    scan_kernel<<<1, 1024, 0, stream>>>(cnt_r, rs_r);
    scan_kernel<<<1, 1024, 0, stream>>>(cnt_g, rs_g);
    dinv_kernel<<<gN, 256, 0, stream>>>(cnt_r, dinv_r);
    dinv_kernel<<<gN, 256, 0, stream>>>(cnt_g, dinv_g);
    place_kernel<<<gE, 256, 0, stream>>>(e_rest, rs_r, cur_r, eslot_r);
    place_kernel<<<gE, 256, 0, stream>>>(e_rig, rs_g, cur_g, eslot_g);

    auto layer = [&](const float* hin, int in_dim, const float* W, const float* b,
                     float* hout, const int* edges, const int* eslot, const int* rs,
                     const float* dinv) {
        gcn_gemm_b<<<N_NODES / 16, 256, 0, stream>>>(hin, W, hw, in_dim);
        gather_kernel<<<N_NODES, H, 0, stream>>>(edges, eslot, rs, hw, dinv, b, hout);
    };

    layer(x_rest, 3, Wr0, br0, h0, e_rest, eslot_r, rs_r, dinv_r);
    layer(h0, H, Wr, br, h1, e_rest, eslot_r, rs_r, dinv_r);
    layer(h1, H, Wr + H * H, br + H, xr, e_rest, eslot_r, rs_r, dinv_r);
    layer(x_rig, 3, Wg0, bg0, h0, e_rig, eslot_g, rs_g, dinv_g);
    layer(h0, H, Wg, bg, h1, e_rig, eslot_g, rs_g, dinv_g);
    layer(h1, H, Wg + H * H, bg + H, xg, e_rig, eslot_g, rs_g, dinv_g);

    // ---- attention ----
    qk_kernel<<<dim3(N_NODES / 16, NHEADS, 2), 256, 0, stream>>>(xr, xg, Wa, ba, Qh, Ql, Khs, Kls);
    zero_pad_k<<<(NHEADS * 16 * H + 255) / 256, 256, 0, stream>>>(Khs, Kls);
    cvt_vt<<<NTILES, 128, 0, stream>>>(xg, Vth, Vtl);
    copy_xr<<<gNH, 256, 0, stream>>>(xr, hcat);
    attn_mfma<<<dim3(94, NHEADS), 128, 0, stream>>>(Qh, Ql, Khs, Kls, Vth, Vtl, hcat);

    // ---- decoder ----
    decoder<<<N_NODES / 8, 256, 0, stream>>>(hcat, Wd0, bd0, Wd, bd, Wout, bout, out);
}

// Round 5
// 707.584 us; speedup vs baseline: 18.3058x; 1.2372x over previous
//
#include <hip/hip_runtime.h>
#include <math.h>

#define N_NODES 6000
#define N_EDGES 192000
#define H 128
#define NHEADS 4
#define HCAT 640
#define NPAD 6016       // K/partial arrays padded to 6016 rows
#define NTILES 188      // ceil(6000/32)

typedef unsigned short ushort_t;
typedef __attribute__((ext_vector_type(8))) short short8;
typedef __attribute__((ext_vector_type(16))) float f32x16;

__device__ __forceinline__ void bf16split(float x, ushort_t& hi, ushort_t& lo) {
    unsigned ub = __float_as_uint(x);
    unsigned hb = ub & 0xffff0000u;
    float l = x - __uint_as_float(hb);
    hi = (ushort_t)(hb >> 16);
    lo = (ushort_t)(__float_as_uint(l) >> 16);
}

__device__ __forceinline__ void gll16(const ushort_t* g, ushort_t* l) {
    __builtin_amdgcn_global_load_lds((const __attribute__((address_space(1))) void*)g,
                                     (__attribute__((address_space(3))) void*)l, 16, 0, 0);
}

// ---------------- CSR build ----------------
__global__ void zero_ints(int* p, int n) {
    int i = blockIdx.x * 256 + threadIdx.x;
    if (i < n) p[i] = 0;
}

__global__ void hist_kernel(const int* __restrict__ edges, int* __restrict__ cnt) {
    int e = blockIdx.x * 256 + threadIdx.x;
    if (e < N_EDGES) atomicAdd(&cnt[edges[N_EDGES + e]], 1);  // target = edges[1]
}

__global__ __launch_bounds__(1024)
void scan_kernel(const int* __restrict__ cnt, int* __restrict__ row_start) {
    __shared__ int ps[1024];
    int t = threadIdx.x;
    int base = t * 6;
    int local[6];
    int s = 0;
#pragma unroll
    for (int j = 0; j < 6; ++j) {
        int idx = base + j;
        int v = (idx < N_NODES) ? cnt[idx] : 0;
        local[j] = s;
        s += v;
    }
    ps[t] = s;
    __syncthreads();
    for (int off = 1; off < 1024; off <<= 1) {
        int v = (t >= off) ? ps[t - off] : 0;
        __syncthreads();
        ps[t] += v;
        __syncthreads();
    }
    int ex = (t > 0) ? ps[t - 1] : 0;
#pragma unroll
    for (int j = 0; j < 6; ++j) {
        int idx = base + j;
        if (idx < N_NODES) row_start[idx] = ex + local[j];
    }
    if (t == 1023) row_start[N_NODES] = ps[1023];
}

__global__ void dinv_kernel(const int* __restrict__ cnt, float* __restrict__ dinv) {
    int i = blockIdx.x * 256 + threadIdx.x;
    if (i < N_NODES) dinv[i] = rsqrtf((float)(cnt[i] + 1));
}

__global__ void place_kernel(const int* __restrict__ edges, const int* __restrict__ row_start,
                             int* __restrict__ cursor, int* __restrict__ eslot) {
    int e = blockIdx.x * 256 + threadIdx.x;
    if (e < N_EDGES) {
        int t = edges[N_EDGES + e];
        int p = atomicAdd(&cursor[t], 1);
        eslot[row_start[t] + p] = e;
    }
}

// ---------------- GCN pieces ----------------
__global__ __launch_bounds__(256)
void gcn_gemm_b(const float* __restrict__ hin, const float* __restrict__ W,
                float* __restrict__ hw, int in_dim) {
    __shared__ float xs[16 * H];
    int n0 = blockIdx.x * 16;
    int t = threadIdx.x;
    int f = t & (H - 1);
    int g = t >> 7;
    for (int i = t; i < 16 * H; i += 256) {
        int r = i >> 7, c = i & (H - 1);
        xs[i] = (c < in_dim) ? hin[(size_t)(n0 + r) * in_dim + c] : 0.f;
    }
    __syncthreads();
    float acc[8];
#pragma unroll
    for (int j = 0; j < 8; ++j) acc[j] = 0.f;
    for (int d = 0; d < in_dim; ++d) {
        float w = W[d * H + f];
#pragma unroll
        for (int j = 0; j < 8; ++j) acc[j] += xs[(g * 8 + j) * H + d] * w;
    }
#pragma unroll
    for (int j = 0; j < 8; ++j) hw[(size_t)(n0 + g * 8 + j) * H + f] = acc[j];
}

__global__ __launch_bounds__(H)
void gather_kernel(const int* __restrict__ edges, const int* __restrict__ eslot,
                   const int* __restrict__ row_start, const float* __restrict__ hw,
                   const float* __restrict__ dinv, const float* __restrict__ b,
                   float* __restrict__ hout) {
    __shared__ int ssrc[128];
    __shared__ float snrm[128];
    int tg = blockIdx.x, f = threadIdx.x;
    int s0 = row_start[tg], s1 = row_start[tg + 1];
    float di = dinv[tg];
    float acc = hw[(size_t)tg * H + f] * di * di;
    for (int base = s0; base < s1; base += 128) {
        int cnt = min(128, s1 - base);
        __syncthreads();
        if (f < cnt) {
            int e = eslot[base + f];
            int s = edges[e];
            ssrc[f] = s;
            snrm[f] = dinv[s] * di;
        }
        __syncthreads();
        for (int i = 0; i < cnt; ++i)
            acc += hw[(size_t)ssrc[i] * H + f] * snrm[i];
    }
    float v = acc + b[f];
    hout[(size_t)tg * H + f] = v > 0.f ? v : 0.f;
}

// ---------------- merged q/k projection: one W read serves q and k ----------------
// grid (375, NHEADS): g=0 half computes Q for 16 nodes from xr, g=1 half K from xg.
__global__ __launch_bounds__(256)
void qk_kernel2(const float* __restrict__ xr, const float* __restrict__ xg,
                const float* __restrict__ Wa, const float* __restrict__ ba,
                ushort_t* __restrict__ Qh, ushort_t* __restrict__ Ql,
                ushort_t* __restrict__ Khs, ushort_t* __restrict__ Kls) {
    __shared__ float xs[2][16][H];   // 16 KB
    int n0 = blockIdx.x * 16, head = blockIdx.y;
    int t = threadIdx.x;
    int f = t & (H - 1);
    int g = t >> 7;                  // 0: Q-from-xr, 1: K-from-xg
    for (int i = t; i < 2 * 16 * H; i += 256) {
        int which = i >> 11;
        int rem = i & 2047;
        xs[which][rem >> 7][rem & 127] = which ? xg[(size_t)n0 * H + rem]
                                               : xr[(size_t)n0 * H + rem];
    }
    __syncthreads();
    const float* W = Wa + (size_t)head * H * H;
    float bias = ba[head * H + f];
    float acc[16];
#pragma unroll
    for (int j = 0; j < 16; ++j) acc[j] = bias;
    for (int d = 0; d < H; ++d) {
        float w = W[d * H + f];
#pragma unroll
        for (int j = 0; j < 16; ++j) acc[j] += xs[g][j][d] * w;
    }
#pragma unroll
    for (int j = 0; j < 16; ++j) {
        int n = n0 + j;
        ushort_t hi, lo;
        bf16split(acc[j], hi, lo);
        if (g == 0) {
            size_t idx = ((size_t)(head * N_NODES + n) << 7) + f;
            Qh[idx] = hi; Ql[idx] = lo;
        } else {
            int pos = (((f >> 3) ^ (n & 15)) << 3) + (f & 7);
            size_t idx = ((size_t)(head * NPAD + n) << 7) + pos;
            Khs[idx] = hi; Kls[idx] = lo;
        }
    }
}

__global__ void zero_pad_k(ushort_t* __restrict__ Khs, ushort_t* __restrict__ Kls) {
    int i = blockIdx.x * 256 + threadIdx.x;
    if (i < NHEADS * 16 * H) {
        int head = i / (16 * H);
        int rest = i - head * 16 * H;
        int n = N_NODES + (rest >> 7);
        int f = rest & 127;
        size_t idx = ((size_t)(head * NPAD + n) << 7) + f;
        Khs[idx] = 0; Kls[idx] = 0;
    }
}

// ---------------- V transpose -> tiled swizzled bf16 hi/lo ----------------
__global__ __launch_bounds__(128)
void cvt_vt(const float* __restrict__ xg, ushort_t* __restrict__ Vth, ushort_t* __restrict__ Vtl) {
    __shared__ float vs[32][129];
    int t0 = blockIdx.x;
    int t = threadIdx.x;
    for (int c = t; c < 32 * 32; c += 128) {
        int row = c >> 5, col4 = (c & 31) << 2;
        int n = t0 * 32 + row;
        float4 v = (n < N_NODES) ? *(const float4*)&xg[(size_t)n * H + col4]
                                 : float4{0.f, 0.f, 0.f, 0.f};
        vs[row][col4 + 0] = v.x; vs[row][col4 + 1] = v.y;
        vs[row][col4 + 2] = v.z; vs[row][col4 + 3] = v.w;
    }
    __syncthreads();
    int d = t;
    size_t base = ((size_t)t0 * H + d) * 32;
#pragma unroll
    for (int oc = 0; oc < 4; ++oc) {
        int cc = oc ^ (d & 3);
        unsigned uh[4], ul[4];
#pragma unroll
        for (int j = 0; j < 4; ++j) {
            ushort_t h0, l0, h1, l1;
            bf16split(vs[cc * 8 + 2 * j][d], h0, l0);
            bf16split(vs[cc * 8 + 2 * j + 1][d], h1, l1);
            uh[j] = (unsigned)h0 | ((unsigned)h1 << 16);
            ul[j] = (unsigned)l0 | ((unsigned)l1 << 16);
        }
        *(uint4*)&Vth[base + oc * 8] = make_uint4(uh[0], uh[1], uh[2], uh[3]);
        *(uint4*)&Vtl[base + oc * 8] = make_uint4(ul[0], ul[1], ul[2], ul[3]);
    }
}

__global__ void copy_xr(const float* __restrict__ xr, float* __restrict__ hcat) {
    int i = blockIdx.x * 256 + threadIdx.x;
    if (i < N_NODES * H) {
        int n = i >> 7, f = i & (H - 1);
        hcat[(size_t)n * HCAT + f] = xr[i];
    }
}

// ---------------- MFMA flash attention, split-K ----------------
// grid (47, NHEADS, NS), block 256 = 4 waves; wave w owns q rows bx*128+w*32..+31.
// Wave w stages array w (Kh,Kl,Vh,Vl) of the shared tile; all 4 waves consume it.
// Writes partial (O, m, l) per split; attn_combine merges.
__global__ __launch_bounds__(256, 2)
void attn_mfma2(const ushort_t* __restrict__ Qh, const ushort_t* __restrict__ Ql,
                const ushort_t* __restrict__ Khs, const ushort_t* __restrict__ Kls,
                const ushort_t* __restrict__ Vth, const ushort_t* __restrict__ Vtl,
                float* __restrict__ Opart, float* __restrict__ mlpart, int tps) {
    __shared__ ushort_t lds[2][4][4096];   // 64 KB
    const int head = blockIdx.y;
    const int sp = blockIdx.z;
    const int t = threadIdx.x;
    const int w = t >> 6;
    const int lane = t & 63;
    const int r = lane & 31;
    const int h = lane >> 5;
    const int q0w = blockIdx.x * 128 + w * 32;

    int t_begin = sp * tps;
    int t_end = t_begin + tps; if (t_end > NTILES) t_end = NTILES;

    // Q B-fragments in registers: rows q0w+r, dims 16s+8h+j
    int qr = q0w + r; if (qr > N_NODES - 1) qr = N_NODES - 1;
    const size_t qbase = ((size_t)(head * N_NODES + qr)) << 7;
    short8 qfh[8], qfl[8];
#pragma unroll
    for (int s = 0; s < 8; ++s) {
        qfh[s] = *(const short8*)&Qh[qbase + 16 * s + 8 * h];
        qfl[s] = *(const short8*)&Ql[qbase + 16 * s + 8 * h];
    }

    f32x16 O[4];
#pragma unroll
    for (int sub = 0; sub < 4; ++sub)
#pragma unroll
        for (int i = 0; i < 16; ++i) O[sub][i] = 0.f;
    float mrun = -1e30f, lrun = 0.f;

    // staging source for this wave (all tiles are 4096 elements)
    const size_t kbase = (size_t)head * NPAD * H;
    const ushort_t* gsrc;
    if (w == 0)      gsrc = Khs + kbase;
    else if (w == 1) gsrc = Kls + kbase;
    else if (w == 2) gsrc = Vth;
    else             gsrc = Vtl;

    // prologue: stage tile t_begin into buf 0
    {
        ushort_t* l = &lds[0][w][0];
        const ushort_t* s = gsrc + (size_t)t_begin * 4096;
#pragma unroll
        for (int i = 0; i < 8; ++i)
            gll16(s + i * 512 + lane * 8, l + i * 512 + lane * 8);
    }

    for (int it = t_begin; it < t_end; ++it) {
        __syncthreads();   // buf[(it-t_begin)&1] ready; prior reads of other buf done
        {
            int nt = it + 1; if (nt >= t_end) nt = t_begin;
            int nb = (it - t_begin + 1) & 1;
            ushort_t* l = &lds[nb][w][0];
            const ushort_t* s = gsrc + (size_t)nt * 4096;
#pragma unroll
            for (int i = 0; i < 8; ++i)
                gll16(s + i * 512 + lane * 8, l + i * 512 + lane * 8);
        }
        const int b = (it - t_begin) & 1;
        const ushort_t* lKh = &lds[b][0][0];
        const ushort_t* lKl = &lds[b][1][0];
        const ushort_t* lVh = &lds[b][2][0];
        const ushort_t* lVl = &lds[b][3][0];

        // ---- S^T = (Kh+Kl)(Qh+Ql)^T, dropping lo*lo ----
        f32x16 acc;
#pragma unroll
        for (int i = 0; i < 16; ++i) acc[i] = 0.f;
        const int krow = r * H;
#pragma unroll
        for (int s = 0; s < 8; ++s) {
            int cc = ((2 * s + h) ^ (r & 15)) << 3;
            short8 ah = *(const short8*)&lKh[krow + cc];
            short8 al = *(const short8*)&lKl[krow + cc];
            acc = __builtin_amdgcn_mfma_f32_32x32x16_bf16(ah, qfh[s], acc, 0, 0, 0);
            acc = __builtin_amdgcn_mfma_f32_32x32x16_bf16(ah, qfl[s], acc, 0, 0, 0);
            acc = __builtin_amdgcn_mfma_f32_32x32x16_bf16(al, qfh[s], acc, 0, 0, 0);
        }

        // ---- online softmax over k for this lane's q (col) ----
        float sv[16];
#pragma unroll
        for (int i = 0; i < 16; ++i) sv[i] = acc[i];
        int klim = N_NODES - (it << 5);
        if (klim < 32) {
#pragma unroll
            for (int i = 0; i < 16; ++i) {
                int row = (i & 3) + 8 * (i >> 2) + 4 * h;
                if (row >= klim) sv[i] = -1e30f;
            }
        }
        float tmax = sv[0];
#pragma unroll
        for (int i = 1; i < 16; ++i) tmax = fmaxf(tmax, sv[i]);
        tmax = fmaxf(tmax, __shfl_xor(tmax, 32));
        float mnew = fmaxf(mrun, tmax);
        float p[16];
        float psum = 0.f;
#pragma unroll
        for (int i = 0; i < 16; ++i) { p[i] = __expf(sv[i] - mnew); psum += p[i]; }
        psum += __shfl_xor(psum, 32);

        // rescale only when some lane's max moved (rare after ~6 tiles)
        if (__ballot(mnew > mrun)) {
            float alpha = __expf(mrun - mnew);
            lrun *= alpha;
#pragma unroll
            for (int i = 0; i < 16; ++i) {
                int rowq = (i & 3) + 8 * (i >> 2) + 4 * h;
                float a = __shfl(alpha, rowq);
#pragma unroll
                for (int sub = 0; sub < 4; ++sub) O[sub][i] *= a;
            }
        }
        lrun += psum;
        mrun = mnew;

        // ---- P (C-layout, transposed) -> A-operand frags via cross-half shfl ----
        float pr[16];
#pragma unroll
        for (int i = 0; i < 16; ++i) pr[i] = __shfl_xor(p[i], 32);
        short8 aPh[2], aPl[2];
#pragma unroll
        for (int s2 = 0; s2 < 2; ++s2) {
#pragma unroll
            for (int j = 0; j < 8; ++j) {
                int c = j & 3;
                float v;
                if (j < 4) v = (h == 0) ? p[c + 8 * s2] : pr[c + 8 * s2 + 4];
                else       v = (h == 1) ? p[c + 8 * s2 + 4] : pr[c + 8 * s2];
                unsigned ub = __float_as_uint(v);
                unsigned hb = ub & 0xffff0000u;
                float lo = v - __uint_as_float(hb);
                aPh[s2][j] = (short)(hb >> 16);
                aPl[s2][j] = (short)(__float_as_uint(lo) >> 16);
            }
        }

        // ---- O += (Ph+Pl)(Vh+Vl), dropping lo*lo ----
#pragma unroll
        for (int sub = 0; sub < 4; ++sub) {
            const int vrow = (32 * sub + r) * 32;
#pragma unroll
            for (int s2 = 0; s2 < 2; ++s2) {
                int cc = (((2 * s2 + h) ^ (r & 3)) << 3);
                short8 bh = *(const short8*)&lVh[vrow + cc];
                short8 bl = *(const short8*)&lVl[vrow + cc];
                O[sub] = __builtin_amdgcn_mfma_f32_32x32x16_bf16(aPh[s2], bh, O[sub], 0, 0, 0);
                O[sub] = __builtin_amdgcn_mfma_f32_32x32x16_bf16(aPh[s2], bl, O[sub], 0, 0, 0);
                O[sub] = __builtin_amdgcn_mfma_f32_32x32x16_bf16(aPl[s2], bh, O[sub], 0, 0, 0);
            }
        }
    }

    // ---- write partials (unnormalized O, plus m,l) ----
    float* Ob = Opart + (size_t)(sp * NHEADS + head) * NPAD * H;
#pragma unroll
    for (int i = 0; i < 16; ++i) {
        int rowq = (i & 3) + 8 * (i >> 2) + 4 * h;
        int qg = q0w + rowq;
        float* dst = &Ob[(size_t)qg * H + r];
#pragma unroll
        for (int sub = 0; sub < 4; ++sub) dst[32 * sub] = O[sub][i];
    }
    if (h == 0) {
        float2* ml = (float2*)mlpart;
        ml[(size_t)(sp * NHEADS + head) * NPAD + q0w + r] = make_float2(mrun, lrun);
    }
}

// merge split-K partials into hcat. grid 12000, block 256; idx=(head*6000+q)*128+d
__global__ __launch_bounds__(256)
void attn_combine(const float* __restrict__ Opart, const float* __restrict__ mlpart,
                  float* __restrict__ hcat, int ns) {
    int idx = blockIdx.x * 256 + threadIdx.x;
    if (idx >= NHEADS * N_NODES * H) return;
    int head = idx / (N_NODES * H);
    int rest = idx - head * N_NODES * H;
    int q = rest >> 7;
    int d = rest & 127;
    const float2* ml = (const float2*)mlpart;
    float m = -1e30f;
    for (int s = 0; s < ns; ++s)
        m = fmaxf(m, ml[(size_t)(s * NHEADS + head) * NPAD + q].x);
    float lsum = 0.f, o = 0.f;
    for (int s = 0; s < ns; ++s) {
        float2 v = ml[(size_t)(s * NHEADS + head) * NPAD + q];
        float wgt = __expf(v.x - m);
        lsum += v.y * wgt;
        o += Opart[((size_t)(s * NHEADS + head) * NPAD + q) * H + d] * wgt;
    }
    hcat[(size_t)q * HCAT + H + head * H + d] = o / lsum;
}

// ---------------- fused decoder MLP (8 nodes/block) ----------------
__global__ __launch_bounds__(256)
void decoder(const float* __restrict__ hcat,
             const float* __restrict__ Wd0, const float* __restrict__ bd0,
             const float* __restrict__ Wd, const float* __restrict__ bd,
             const float* __restrict__ Wout, const float* __restrict__ bout,
             float* __restrict__ out) {
    __shared__ float s0[8 * HCAT];
    __shared__ float s1[8 * H];
    __shared__ float s2[8 * H];
    int n0 = blockIdx.x * 8;
    int t = threadIdx.x;
    int f = t & (H - 1);
    int g = t >> 7;
    for (int i = t; i < 8 * HCAT; i += 256)
        s0[i] = hcat[(size_t)n0 * HCAT + i];
    __syncthreads();

    float acc[4];
#pragma unroll
    for (int j = 0; j < 4; ++j) acc[j] = bd0[f];
    for (int d = 0; d < HCAT; ++d) {
        float w = Wd0[d * H + f];
#pragma unroll
        for (int j = 0; j < 4; ++j) acc[j] += s0[(g * 4 + j) * HCAT + d] * w;
    }
#pragma unroll
    for (int j = 0; j < 4; ++j) s1[(g * 4 + j) * H + f] = fmaxf(acc[j], 0.f);
    __syncthreads();

#pragma unroll
    for (int j = 0; j < 4; ++j) acc[j] = bd[f];
    for (int d = 0; d < H; ++d) {
        float w = Wd[d * H + f];
#pragma unroll
        for (int j = 0; j < 4; ++j) acc[j] += s1[(g * 4 + j) * H + d] * w;
    }
#pragma unroll
    for (int j = 0; j < 4; ++j) s2[(g * 4 + j) * H + f] = fmaxf(acc[j], 0.f);
    __syncthreads();

#pragma unroll
    for (int j = 0; j < 4; ++j) acc[j] = bd[H + f];
    for (int d = 0; d < H; ++d) {
        float w = Wd[H * H + d * H + f];
#pragma unroll
        for (int j = 0; j < 4; ++j) acc[j] += s2[(g * 4 + j) * H + d] * w;
    }
    __syncthreads();
#pragma unroll
    for (int j = 0; j < 4; ++j) s1[(g * 4 + j) * H + f] = fmaxf(acc[j], 0.f);
    __syncthreads();

    if (t < 24) {
        int n = t / 3, c = t % 3;
        float o = bout[c];
        for (int d = 0; d < H; ++d) o += s1[n * H + d] * Wout[d * 3 + c];
        out[(size_t)(n0 + n) * 3 + c] = o;
    }
}

// ---------------- launch ----------------
extern "C" void kernel_launch(void* const* d_in, const int* in_sizes, int n_in,
                              void* d_out, int out_size, void* d_ws, size_t ws_size,
                              hipStream_t stream) {
    const float* x_rest = (const float*)d_in[0];
    const float* x_rig  = (const float*)d_in[1];
    const int*   e_rest = (const int*)d_in[2];
    const int*   e_rig  = (const int*)d_in[3];
    const float* Wr0 = (const float*)d_in[4];
    const float* br0 = (const float*)d_in[5];
    const float* Wr  = (const float*)d_in[6];
    const float* br  = (const float*)d_in[7];
    const float* Wg0 = (const float*)d_in[8];
    const float* bg0 = (const float*)d_in[9];
    const float* Wg  = (const float*)d_in[10];
    const float* bg  = (const float*)d_in[11];
    const float* Wa  = (const float*)d_in[12];
    const float* ba  = (const float*)d_in[13];
    const float* Wd0 = (const float*)d_in[14];
    const float* bd0 = (const float*)d_in[15];
    const float* Wd  = (const float*)d_in[16];
    const float* bd  = (const float*)d_in[17];
    const float* Wout = (const float*)d_in[18];
    const float* bout = (const float*)d_in[19];
    float* out = (float*)d_out;

    const size_t NH = (size_t)N_NODES * H;
    float* ws = (float*)d_ws;
    float* dinv_r = ws;
    float* dinv_g = dinv_r + N_NODES;
    float* hw     = dinv_g + N_NODES;
    float* h0     = hw + NH;
    float* h1     = h0 + NH;
    float* xr     = h1 + NH;
    float* xg     = xr + NH;
    float* hcat   = xg + NH;
    ushort_t* Qh  = (ushort_t*)(hcat + (size_t)N_NODES * HCAT);
    ushort_t* Ql  = Qh + (size_t)NHEADS * N_NODES * H;
    ushort_t* Khs = Ql + (size_t)NHEADS * N_NODES * H;
    ushort_t* Kls = Khs + (size_t)NHEADS * NPAD * H;
    ushort_t* Vth = Kls + (size_t)NHEADS * NPAD * H;
    ushort_t* Vtl = Vth + (size_t)NTILES * H * 32;
    int* ib       = (int*)(Vtl + (size_t)NTILES * H * 32);
    int* cnt_r    = ib;
    int* cnt_g    = cnt_r + N_NODES;
    int* cur_r    = cnt_g + N_NODES;
    int* cur_g    = cur_r + N_NODES;
    int* rs_r     = cur_g + N_NODES;
    int* rs_g     = rs_r + N_NODES + 1;
    int* eslot_r  = rs_g + N_NODES + 1;
    int* eslot_g  = eslot_r + N_EDGES;
    int* iend     = eslot_g + N_EDGES;
    float* Opart  = (float*)(((uintptr_t)iend + 15) & ~(uintptr_t)15);

    // pick split factor by available workspace
    size_t base_bytes = (size_t)((char*)Opart - (char*)d_ws);
    size_t per_split  = (size_t)NHEADS * NPAD * (H + 2) * sizeof(float);
    int NS = 2;
    if (ws_size >= base_bytes + 4 * per_split + (1u << 20)) NS = 4;
    float* mlpart = Opart + (size_t)NS * NHEADS * NPAD * H;
    int tps = (NTILES + NS - 1) / NS;

    const int gN  = (N_NODES + 255) / 256;
    const int gE  = (N_EDGES + 255) / 256;
    const int gNH = (N_NODES * H + 255) / 256;

    // ---- CSR build ----
    zero_ints<<<(4 * N_NODES + 255) / 256, 256, 0, stream>>>(cnt_r, 4 * N_NODES);
    hist_kernel<<<gE, 256, 0, stream>>>(e_rest, cnt_r);
    hist_kernel<<<gE, 256, 0, stream>>>(e_rig, cnt_g);
    scan_kernel<<<1, 1024, 0, stream>>>(cnt_r, rs_r);
    scan_kernel<<<1, 1024, 0, stream>>>(cnt_g, rs_g);
    dinv_kernel<<<gN, 256, 0, stream>>>(cnt_r, dinv_r);
    dinv_kernel<<<gN, 256, 0, stream>>>(cnt_g, dinv_g);
    place_kernel<<<gE, 256, 0, stream>>>(e_rest, rs_r, cur_r, eslot_r);
    place_kernel<<<gE, 256, 0, stream>>>(e_rig, rs_g, cur_g, eslot_g);

    auto layer = [&](const float* hin, int in_dim, const float* W, const float* b,
                     float* hout, const int* edges, const int* eslot, const int* rs,
                     const float* dinv) {
        gcn_gemm_b<<<N_NODES / 16, 256, 0, stream>>>(hin, W, hw, in_dim);
        gather_kernel<<<N_NODES, H, 0, stream>>>(edges, eslot, rs, hw, dinv, b, hout);
    };

    layer(x_rest, 3, Wr0, br0, h0, e_rest, eslot_r, rs_r, dinv_r);
    layer(h0, H, Wr, br, h1, e_rest, eslot_r, rs_r, dinv_r);
    layer(h1, H, Wr + H * H, br + H, xr, e_rest, eslot_r, rs_r, dinv_r);
    layer(x_rig, 3, Wg0, bg0, h0, e_rig, eslot_g, rs_g, dinv_g);
    layer(h0, H, Wg, bg, h1, e_rig, eslot_g, rs_g, dinv_g);
    layer(h1, H, Wg + H * H, bg + H, xg, e_rig, eslot_g, rs_g, dinv_g);

    // ---- attention ----
    qk_kernel2<<<dim3(N_NODES / 16, NHEADS), 256, 0, stream>>>(xr, xg, Wa, ba, Qh, Ql, Khs, Kls);
    zero_pad_k<<<(NHEADS * 16 * H + 255) / 256, 256, 0, stream>>>(Khs, Kls);
    cvt_vt<<<NTILES, 128, 0, stream>>>(xg, Vth, Vtl);
    copy_xr<<<gNH, 256, 0, stream>>>(xr, hcat);
    attn_mfma2<<<dim3(47, NHEADS, NS), 256, 0, stream>>>(Qh, Ql, Khs, Kls, Vth, Vtl,
                                                         Opart, mlpart, tps);
    attn_combine<<<(NHEADS * N_NODES * H) / 256, 256, 0, stream>>>(Opart, mlpart, hcat, NS);

    // ---- decoder ----
    decoder<<<N_NODES / 8, 256, 0, stream>>>(hcat, Wd0, bd0, Wd, bd, Wout, bout, out);
}

// Round 6
// 621.340 us; speedup vs baseline: 20.8468x; 1.1388x over previous
//
#include <hip/hip_runtime.h>
#include <math.h>

#define N_NODES 6000
#define N_EDGES 192000
#define H 128
#define NHEADS 4
#define HCAT 640
#define NPAD 6016       // K/partial arrays padded to 6016 rows
#define NTILES 188      // ceil(6000/32)

typedef unsigned short ushort_t;
typedef __attribute__((ext_vector_type(8))) short short8;
typedef __attribute__((ext_vector_type(16))) float f32x16;

__device__ __forceinline__ void bf16split(float x, ushort_t& hi, ushort_t& lo) {
    unsigned ub = __float_as_uint(x);
    unsigned hb = ub & 0xffff0000u;
    float l = x - __uint_as_float(hb);
    hi = (ushort_t)(hb >> 16);
    lo = (ushort_t)(__float_as_uint(l) >> 16);
}

__device__ __forceinline__ void gll16(const ushort_t* g, ushort_t* l) {
    __builtin_amdgcn_global_load_lds((const __attribute__((address_space(1))) void*)g,
                                     (__attribute__((address_space(3))) void*)l, 16, 0, 0);
}

// ---------------- CSR build (both graphs per launch) ----------------
__global__ void zero_ints(int* p, int n) {
    int i = blockIdx.x * 256 + threadIdx.x;
    if (i < n) p[i] = 0;
}

__global__ void hist2(const int* __restrict__ eA, const int* __restrict__ eB,
                      int* __restrict__ cnt) {
    int e = blockIdx.x * 256 + threadIdx.x;
    int z = blockIdx.y;
    const int* edges = z ? eB : eA;
    if (e < N_EDGES) atomicAdd(&cnt[z * N_NODES + edges[N_EDGES + e]], 1);
}

// grid 2 (one block per graph), 1024 threads: exclusive prefix over 6000 counts
__global__ __launch_bounds__(1024)
void scan2(const int* __restrict__ cnt_all, int* __restrict__ rs_all) {
    __shared__ int ps[1024];
    int z = blockIdx.x;
    const int* cnt = cnt_all + z * N_NODES;
    int* row_start = rs_all + z * (N_NODES + 1);
    int t = threadIdx.x;
    int base = t * 6;
    int local[6];
    int s = 0;
#pragma unroll
    for (int j = 0; j < 6; ++j) {
        int idx = base + j;
        int v = (idx < N_NODES) ? cnt[idx] : 0;
        local[j] = s;
        s += v;
    }
    ps[t] = s;
    __syncthreads();
    for (int off = 1; off < 1024; off <<= 1) {
        int v = (t >= off) ? ps[t - off] : 0;
        __syncthreads();
        ps[t] += v;
        __syncthreads();
    }
    int ex = (t > 0) ? ps[t - 1] : 0;
#pragma unroll
    for (int j = 0; j < 6; ++j) {
        int idx = base + j;
        if (idx < N_NODES) row_start[idx] = ex + local[j];
    }
    if (t == 1023) row_start[N_NODES] = ps[1023];
}

__global__ void dinv_kernel(const int* __restrict__ cnt, float* __restrict__ dinv, int n) {
    int i = blockIdx.x * 256 + threadIdx.x;
    if (i < n) dinv[i] = rsqrtf((float)(cnt[i] + 1));
}

__global__ void place2(const int* __restrict__ eA, const int* __restrict__ eB,
                       const int* __restrict__ rs_all, int* __restrict__ cur_all,
                       int* __restrict__ eslot_all) {
    int e = blockIdx.x * 256 + threadIdx.x;
    int z = blockIdx.y;
    const int* edges = z ? eB : eA;
    if (e < N_EDGES) {
        int tg = edges[N_EDGES + e];
        int p = atomicAdd(&cur_all[z * N_NODES + tg], 1);
        eslot_all[(size_t)z * N_EDGES + rs_all[z * (N_NODES + 1) + tg] + p] = e;
    }
}

// ---------------- GCN pieces (both graphs per launch) ----------------
// grid (375, 2), block 256
__global__ __launch_bounds__(256)
void gcn_gemm2(const float* __restrict__ hinA, const float* __restrict__ hinB,
               const float* __restrict__ WA, const float* __restrict__ WB,
               float* __restrict__ hwA, float* __restrict__ hwB, int in_dim) {
    __shared__ float xs[16 * H];
    int z = blockIdx.y;
    const float* hin = z ? hinB : hinA;
    const float* W = z ? WB : WA;
    float* hw = z ? hwB : hwA;
    int n0 = blockIdx.x * 16;
    int t = threadIdx.x;
    int f = t & (H - 1);
    int g = t >> 7;
    for (int i = t; i < 16 * H; i += 256) {
        int r = i >> 7, c = i & (H - 1);
        xs[i] = (c < in_dim) ? hin[(size_t)(n0 + r) * in_dim + c] : 0.f;
    }
    __syncthreads();
    float acc[8];
#pragma unroll
    for (int j = 0; j < 8; ++j) acc[j] = 0.f;
    for (int d = 0; d < in_dim; ++d) {
        float w = W[d * H + f];
#pragma unroll
        for (int j = 0; j < 8; ++j) acc[j] += xs[(g * 8 + j) * H + d] * w;
    }
#pragma unroll
    for (int j = 0; j < 8; ++j) hw[(size_t)(n0 + g * 8 + j) * H + f] = acc[j];
}

// grid (6000, 2), block 128. Output stride selectable (to write hcat directly).
__global__ __launch_bounds__(H)
void gather2(const int* __restrict__ eA, const int* __restrict__ eB,
             const int* __restrict__ eslot_all, const int* __restrict__ rs_all,
             const float* __restrict__ hwA, const float* __restrict__ hwB,
             const float* __restrict__ dinv_all,
             const float* __restrict__ bA, const float* __restrict__ bB,
             float* __restrict__ outA, float* __restrict__ outB, int osA, int osB) {
    __shared__ int ssrc[128];
    __shared__ float snrm[128];
    int z = blockIdx.y;
    const int* edges = z ? eB : eA;
    const int* eslot = eslot_all + (size_t)z * N_EDGES;
    const int* row_start = rs_all + z * (N_NODES + 1);
    const float* hw = z ? hwB : hwA;
    const float* dinv = dinv_all + z * N_NODES;
    const float* b = z ? bB : bA;
    float* out = z ? outB : outA;
    int ostride = z ? osB : osA;

    int tg = blockIdx.x, f = threadIdx.x;
    int s0 = row_start[tg], s1 = row_start[tg + 1];
    float di = dinv[tg];
    float acc = hw[(size_t)tg * H + f] * di * di;
    for (int base = s0; base < s1; base += 128) {
        int cnt = min(128, s1 - base);
        __syncthreads();
        if (f < cnt) {
            int e = eslot[base + f];
            int s = edges[e];
            ssrc[f] = s;
            snrm[f] = dinv[s] * di;
        }
        __syncthreads();
        for (int i = 0; i < cnt; ++i)
            acc += hw[(size_t)ssrc[i] * H + f] * snrm[i];
    }
    float v = acc + b[f];
    out[(size_t)tg * ostride + f] = v > 0.f ? v : 0.f;
}

// ---------------- merged q/k projection ----------------
// grid (375, NHEADS): g=0 half computes Q (from qs, stride qstride), g=1 half K from xg.
__global__ __launch_bounds__(256)
void qk_kernel2(const float* __restrict__ qs, int qstride, const float* __restrict__ xg,
                const float* __restrict__ Wa, const float* __restrict__ ba,
                ushort_t* __restrict__ Qh, ushort_t* __restrict__ Ql,
                ushort_t* __restrict__ Khs, ushort_t* __restrict__ Kls) {
    __shared__ float xs[2][16][H];
    int n0 = blockIdx.x * 16, head = blockIdx.y;
    int t = threadIdx.x;
    int f = t & (H - 1);
    int g = t >> 7;
    for (int i = t; i < 2 * 16 * H; i += 256) {
        int which = i >> 11;
        int rem = i & 2047;
        int row = rem >> 7, col = rem & 127;
        xs[which][row][col] = which ? xg[(size_t)(n0 + row) * H + col]
                                    : qs[(size_t)(n0 + row) * qstride + col];
    }
    __syncthreads();
    const float* W = Wa + (size_t)head * H * H;
    float bias = ba[head * H + f];
    float acc[16];
#pragma unroll
    for (int j = 0; j < 16; ++j) acc[j] = bias;
    for (int d = 0; d < H; ++d) {
        float w = W[d * H + f];
#pragma unroll
        for (int j = 0; j < 16; ++j) acc[j] += xs[g][j][d] * w;
    }
#pragma unroll
    for (int j = 0; j < 16; ++j) {
        int n = n0 + j;
        ushort_t hi, lo;
        bf16split(acc[j], hi, lo);
        if (g == 0) {
            size_t idx = ((size_t)(head * N_NODES + n) << 7) + f;
            Qh[idx] = hi; Ql[idx] = lo;
        } else {
            int pos = (((f >> 3) ^ (n & 15)) << 3) + (f & 7);
            size_t idx = ((size_t)(head * NPAD + n) << 7) + pos;
            Khs[idx] = hi; Kls[idx] = lo;
        }
    }
}

__global__ void zero_pad_k(ushort_t* __restrict__ Khs, ushort_t* __restrict__ Kls) {
    int i = blockIdx.x * 256 + threadIdx.x;
    if (i < NHEADS * 16 * H) {
        int head = i / (16 * H);
        int rest = i - head * 16 * H;
        int n = N_NODES + (rest >> 7);
        int f = rest & 127;
        size_t idx = ((size_t)(head * NPAD + n) << 7) + f;
        Khs[idx] = 0; Kls[idx] = 0;
    }
}

// ---------------- V transpose -> tiled swizzled bf16 hi/lo ----------------
__global__ __launch_bounds__(128)
void cvt_vt(const float* __restrict__ xg, ushort_t* __restrict__ Vth, ushort_t* __restrict__ Vtl) {
    __shared__ float vs[32][129];
    int t0 = blockIdx.x;
    int t = threadIdx.x;
    for (int c = t; c < 32 * 32; c += 128) {
        int row = c >> 5, col4 = (c & 31) << 2;
        int n = t0 * 32 + row;
        float4 v = (n < N_NODES) ? *(const float4*)&xg[(size_t)n * H + col4]
                                 : float4{0.f, 0.f, 0.f, 0.f};
        vs[row][col4 + 0] = v.x; vs[row][col4 + 1] = v.y;
        vs[row][col4 + 2] = v.z; vs[row][col4 + 3] = v.w;
    }
    __syncthreads();
    int d = t;
    size_t base = ((size_t)t0 * H + d) * 32;
#pragma unroll
    for (int oc = 0; oc < 4; ++oc) {
        int cc = oc ^ (d & 3);
        unsigned uh[4], ul[4];
#pragma unroll
        for (int j = 0; j < 4; ++j) {
            ushort_t h0, l0, h1, l1;
            bf16split(vs[cc * 8 + 2 * j][d], h0, l0);
            bf16split(vs[cc * 8 + 2 * j + 1][d], h1, l1);
            uh[j] = (unsigned)h0 | ((unsigned)h1 << 16);
            ul[j] = (unsigned)l0 | ((unsigned)l1 << 16);
        }
        *(uint4*)&Vth[base + oc * 8] = make_uint4(uh[0], uh[1], uh[2], uh[3]);
        *(uint4*)&Vtl[base + oc * 8] = make_uint4(ul[0], ul[1], ul[2], ul[3]);
    }
}

// ---------------- MFMA flash attention, split-K, 48 KB LDS ----------------
// grid (47, NHEADS, NS), block 256 = 4 waves; wave w owns q rows bx*128+w*32..+31.
// K double-buffered (32 KB), V single-buffered (16 KB), two barriers per tile:
//   syncA: K[b] ready, prev PV done  -> prefetch V(it) -> S + softmax
//   syncB: V ready, K[b] reads done  -> prefetch K[b^1](it+1) -> PV
// 48 KB -> 3 blocks/CU -> 752 blocks in one pass.
__global__ __launch_bounds__(256, 3)
void attn_mfma3(const ushort_t* __restrict__ Qh, const ushort_t* __restrict__ Ql,
                const ushort_t* __restrict__ Khs, const ushort_t* __restrict__ Kls,
                const ushort_t* __restrict__ Vth, const ushort_t* __restrict__ Vtl,
                float* __restrict__ Opart, float* __restrict__ mlpart, int tps) {
    __shared__ ushort_t Kbuf[2][2][4096];   // [buf][hi/lo] 32 KB
    __shared__ ushort_t Vbuf[2][4096];      // [hi/lo] 16 KB
    const int head = blockIdx.y;
    const int sp = blockIdx.z;
    const int t = threadIdx.x;
    const int w = t >> 6;
    const int lane = t & 63;
    const int r = lane & 31;
    const int h = lane >> 5;
    const int q0w = blockIdx.x * 128 + w * 32;

    int t_begin = sp * tps;
    int t_end = t_begin + tps; if (t_end > NTILES) t_end = NTILES;

    // staging roles: waves 0,1 -> hi arrays; waves 2,3 -> lo arrays
    const int khl = w >> 1;
    const int wseg = (w & 1) * 4;
    const size_t kbase = (size_t)head * NPAD * H;
    const ushort_t* gK = (khl ? Kls : Khs) + kbase;
    const ushort_t* gV = khl ? Vtl : Vth;

    // Q B-fragments in registers: rows q0w+r, dims 16s+8h+j
    int qr = q0w + r; if (qr > N_NODES - 1) qr = N_NODES - 1;
    const size_t qbase = ((size_t)(head * N_NODES + qr)) << 7;
    short8 qfh[8], qfl[8];
#pragma unroll
    for (int s = 0; s < 8; ++s) {
        qfh[s] = *(const short8*)&Qh[qbase + 16 * s + 8 * h];
        qfl[s] = *(const short8*)&Ql[qbase + 16 * s + 8 * h];
    }

    f32x16 O[4];
#pragma unroll
    for (int sub = 0; sub < 4; ++sub)
#pragma unroll
        for (int i = 0; i < 16; ++i) O[sub][i] = 0.f;
    float mrun = -1e30f, lrun = 0.f;

    // prologue: stage K tile t_begin into buf 0
    {
        const ushort_t* src = gK + (size_t)t_begin * 4096;
        ushort_t* dst = &Kbuf[0][khl][0];
#pragma unroll
        for (int s = 0; s < 4; ++s) {
            int off = (wseg + s) * 512 + lane * 8;
            gll16(src + off, dst + off);
        }
    }

    for (int it = t_begin; it < t_end; ++it) {
        const int b = (it - t_begin) & 1;
        __syncthreads();   // K[b] ready; previous PV reads of Vbuf complete
        {   // prefetch V for current tile
            const ushort_t* src = gV + (size_t)it * 4096;
            ushort_t* dst = &Vbuf[khl][0];
#pragma unroll
            for (int s = 0; s < 4; ++s) {
                int off = (wseg + s) * 512 + lane * 8;
                gll16(src + off, dst + off);
            }
        }
        const ushort_t* lKh = &Kbuf[b][0][0];
        const ushort_t* lKl = &Kbuf[b][1][0];

        // ---- S^T = (Kh+Kl)(Qh+Ql)^T, dropping lo*lo ----
        f32x16 acc;
#pragma unroll
        for (int i = 0; i < 16; ++i) acc[i] = 0.f;
        const int krow = r * H;
#pragma unroll
        for (int s = 0; s < 8; ++s) {
            int cc = ((2 * s + h) ^ (r & 15)) << 3;
            short8 ah = *(const short8*)&lKh[krow + cc];
            short8 al = *(const short8*)&lKl[krow + cc];
            acc = __builtin_amdgcn_mfma_f32_32x32x16_bf16(ah, qfh[s], acc, 0, 0, 0);
            acc = __builtin_amdgcn_mfma_f32_32x32x16_bf16(ah, qfl[s], acc, 0, 0, 0);
            acc = __builtin_amdgcn_mfma_f32_32x32x16_bf16(al, qfh[s], acc, 0, 0, 0);
        }

        // ---- online softmax ----
        float sv[16];
#pragma unroll
        for (int i = 0; i < 16; ++i) sv[i] = acc[i];
        int klim = N_NODES - (it << 5);
        if (klim < 32) {
#pragma unroll
            for (int i = 0; i < 16; ++i) {
                int row = (i & 3) + 8 * (i >> 2) + 4 * h;
                if (row >= klim) sv[i] = -1e30f;
            }
        }
        float tmax = sv[0];
#pragma unroll
        for (int i = 1; i < 16; ++i) tmax = fmaxf(tmax, sv[i]);
        tmax = fmaxf(tmax, __shfl_xor(tmax, 32));
        float mnew = fmaxf(mrun, tmax);
        float p[16];
        float psum = 0.f;
#pragma unroll
        for (int i = 0; i < 16; ++i) { p[i] = __expf(sv[i] - mnew); psum += p[i]; }
        psum += __shfl_xor(psum, 32);

        if (__ballot(mnew > mrun)) {
            float alpha = __expf(mrun - mnew);
            lrun *= alpha;
#pragma unroll
            for (int i = 0; i < 16; ++i) {
                int rowq = (i & 3) + 8 * (i >> 2) + 4 * h;
                float a = __shfl(alpha, rowq);
#pragma unroll
                for (int sub = 0; sub < 4; ++sub) O[sub][i] *= a;
            }
        }
        lrun += psum;
        mrun = mnew;

        // ---- P repack: C-layout (transposed) -> A-operand frags ----
        float pr[16];
#pragma unroll
        for (int i = 0; i < 16; ++i) pr[i] = __shfl_xor(p[i], 32);
        short8 aPh[2], aPl[2];
#pragma unroll
        for (int s2 = 0; s2 < 2; ++s2) {
#pragma unroll
            for (int j = 0; j < 8; ++j) {
                int c = j & 3;
                float v;
                if (j < 4) v = (h == 0) ? p[c + 8 * s2] : pr[c + 8 * s2 + 4];
                else       v = (h == 1) ? p[c + 8 * s2 + 4] : pr[c + 8 * s2];
                unsigned ub = __float_as_uint(v);
                unsigned hb = ub & 0xffff0000u;
                float lo = v - __uint_as_float(hb);
                aPh[s2][j] = (short)(hb >> 16);
                aPl[s2][j] = (short)(__float_as_uint(lo) >> 16);
            }
        }

        __syncthreads();   // Vbuf ready; all waves done reading Kbuf[b]
        if (it + 1 < t_end) {   // prefetch next K into other buffer
            const ushort_t* src = gK + (size_t)(it + 1) * 4096;
            ushort_t* dst = &Kbuf[b ^ 1][khl][0];
#pragma unroll
            for (int s = 0; s < 4; ++s) {
                int off = (wseg + s) * 512 + lane * 8;
                gll16(src + off, dst + off);
            }
        }

        // ---- O += (Ph+Pl)(Vh+Vl), dropping lo*lo ----
        const ushort_t* lVh = &Vbuf[0][0];
        const ushort_t* lVl = &Vbuf[1][0];
#pragma unroll
        for (int sub = 0; sub < 4; ++sub) {
            const int vrow = (32 * sub + r) * 32;
#pragma unroll
            for (int s2 = 0; s2 < 2; ++s2) {
                int cc = (((2 * s2 + h) ^ (r & 3)) << 3);
                short8 bh = *(const short8*)&lVh[vrow + cc];
                short8 bl = *(const short8*)&lVl[vrow + cc];
                O[sub] = __builtin_amdgcn_mfma_f32_32x32x16_bf16(aPh[s2], bh, O[sub], 0, 0, 0);
                O[sub] = __builtin_amdgcn_mfma_f32_32x32x16_bf16(aPh[s2], bl, O[sub], 0, 0, 0);
                O[sub] = __builtin_amdgcn_mfma_f32_32x32x16_bf16(aPl[s2], bh, O[sub], 0, 0, 0);
            }
        }
    }

    // ---- write partials ----
    float* Ob = Opart + (size_t)(sp * NHEADS + head) * NPAD * H;
#pragma unroll
    for (int i = 0; i < 16; ++i) {
        int rowq = (i & 3) + 8 * (i >> 2) + 4 * h;
        int qg = q0w + rowq;
        float* dst = &Ob[(size_t)qg * H + r];
#pragma unroll
        for (int sub = 0; sub < 4; ++sub) dst[32 * sub] = O[sub][i];
    }
    if (h == 0) {
        float2* ml = (float2*)mlpart;
        ml[(size_t)(sp * NHEADS + head) * NPAD + q0w + r] = make_float2(mrun, lrun);
    }
}

// merge split-K partials into hcat (float4). grid over NHEADS*N*H/4.
__global__ __launch_bounds__(256)
void attn_combine(const float* __restrict__ Opart, const float* __restrict__ mlpart,
                  float* __restrict__ hcat, int ns) {
    int idx = blockIdx.x * 256 + threadIdx.x;
    if (idx >= NHEADS * N_NODES * (H / 4)) return;
    int head = idx / (N_NODES * (H / 4));
    int rest = idx - head * N_NODES * (H / 4);
    int q = rest >> 5;
    int d4 = (rest & 31) << 2;
    const float2* ml = (const float2*)mlpart;
    float m = -1e30f;
    for (int s = 0; s < ns; ++s)
        m = fmaxf(m, ml[(size_t)(s * NHEADS + head) * NPAD + q].x);
    float lsum = 0.f;
    float4 o = {0.f, 0.f, 0.f, 0.f};
    for (int s = 0; s < ns; ++s) {
        float2 v = ml[(size_t)(s * NHEADS + head) * NPAD + q];
        float wgt = __expf(v.x - m);
        lsum += v.y * wgt;
        float4 ov = *(const float4*)&Opart[((size_t)(s * NHEADS + head) * NPAD + q) * H + d4];
        o.x += ov.x * wgt; o.y += ov.y * wgt; o.z += ov.z * wgt; o.w += ov.w * wgt;
    }
    float inv = 1.f / lsum;
    float4 res = {o.x * inv, o.y * inv, o.z * inv, o.w * inv};
    *(float4*)&hcat[(size_t)q * HCAT + H + head * H + d4] = res;
}

// ---------------- fused decoder MLP (8 nodes/block) ----------------
__global__ __launch_bounds__(256)
void decoder(const float* __restrict__ hcat,
             const float* __restrict__ Wd0, const float* __restrict__ bd0,
             const float* __restrict__ Wd, const float* __restrict__ bd,
             const float* __restrict__ Wout, const float* __restrict__ bout,
             float* __restrict__ out) {
    __shared__ float s0[8 * HCAT];
    __shared__ float s1[8 * H];
    __shared__ float s2[8 * H];
    int n0 = blockIdx.x * 8;
    int t = threadIdx.x;
    int f = t & (H - 1);
    int g = t >> 7;
    for (int i = t; i < 8 * HCAT; i += 256)
        s0[i] = hcat[(size_t)n0 * HCAT + i];
    __syncthreads();

    float acc[4];
#pragma unroll
    for (int j = 0; j < 4; ++j) acc[j] = bd0[f];
    for (int d = 0; d < HCAT; ++d) {
        float w = Wd0[d * H + f];
#pragma unroll
        for (int j = 0; j < 4; ++j) acc[j] += s0[(g * 4 + j) * HCAT + d] * w;
    }
#pragma unroll
    for (int j = 0; j < 4; ++j) s1[(g * 4 + j) * H + f] = fmaxf(acc[j], 0.f);
    __syncthreads();

#pragma unroll
    for (int j = 0; j < 4; ++j) acc[j] = bd[f];
    for (int d = 0; d < H; ++d) {
        float w = Wd[d * H + f];
#pragma unroll
        for (int j = 0; j < 4; ++j) acc[j] += s1[(g * 4 + j) * H + d] * w;
    }
#pragma unroll
    for (int j = 0; j < 4; ++j) s2[(g * 4 + j) * H + f] = fmaxf(acc[j], 0.f);
    __syncthreads();

#pragma unroll
    for (int j = 0; j < 4; ++j) acc[j] = bd[H + f];
    for (int d = 0; d < H; ++d) {
        float w = Wd[H * H + d * H + f];
#pragma unroll
        for (int j = 0; j < 4; ++j) acc[j] += s2[(g * 4 + j) * H + d] * w;
    }
    __syncthreads();
#pragma unroll
    for (int j = 0; j < 4; ++j) s1[(g * 4 + j) * H + f] = fmaxf(acc[j], 0.f);
    __syncthreads();

    if (t < 24) {
        int n = t / 3, c = t % 3;
        float o = bout[c];
        for (int d = 0; d < H; ++d) o += s1[n * H + d] * Wout[d * 3 + c];
        out[(size_t)(n0 + n) * 3 + c] = o;
    }
}

// ---------------- launch ----------------
extern "C" void kernel_launch(void* const* d_in, const int* in_sizes, int n_in,
                              void* d_out, int out_size, void* d_ws, size_t ws_size,
                              hipStream_t stream) {
    const float* x_rest = (const float*)d_in[0];
    const float* x_rig  = (const float*)d_in[1];
    const int*   e_rest = (const int*)d_in[2];
    const int*   e_rig  = (const int*)d_in[3];
    const float* Wr0 = (const float*)d_in[4];
    const float* br0 = (const float*)d_in[5];
    const float* Wr  = (const float*)d_in[6];
    const float* br  = (const float*)d_in[7];
    const float* Wg0 = (const float*)d_in[8];
    const float* bg0 = (const float*)d_in[9];
    const float* Wg  = (const float*)d_in[10];
    const float* bg  = (const float*)d_in[11];
    const float* Wa  = (const float*)d_in[12];
    const float* ba  = (const float*)d_in[13];
    const float* Wd0 = (const float*)d_in[14];
    const float* bd0 = (const float*)d_in[15];
    const float* Wd  = (const float*)d_in[16];
    const float* bd  = (const float*)d_in[17];
    const float* Wout = (const float*)d_in[18];
    const float* bout = (const float*)d_in[19];
    float* out = (float*)d_out;

    const size_t NH = (size_t)N_NODES * H;
    float* ws = (float*)d_ws;
    float* dinv = ws;                      // 2N (resting, rigid)
    float* hw   = dinv + 2 * N_NODES;      // 2*NH
    float* hb   = hw + 2 * NH;             // 2*NH
    float* hcat = hb + 2 * NH;             // N*HCAT
    float* ha   = hcat;                    // alias: dead before hcat is written
    float* xg   = hb + NH;                 // alias hb_g: dead before L3 gather writes it
    ushort_t* Qh  = (ushort_t*)(hcat + (size_t)N_NODES * HCAT);
    ushort_t* Ql  = Qh + (size_t)NHEADS * N_NODES * H;
    ushort_t* Khs = Ql + (size_t)NHEADS * N_NODES * H;
    ushort_t* Kls = Khs + (size_t)NHEADS * NPAD * H;
    ushort_t* Vth = Kls + (size_t)NHEADS * NPAD * H;
    ushort_t* Vtl = Vth + (size_t)NTILES * H * 32;
    int* ib   = (int*)(Vtl + (size_t)NTILES * H * 32);
    int* cnt  = ib;                        // 2N
    int* cur  = cnt + 2 * N_NODES;         // 2N
    int* rs   = cur + 2 * N_NODES;         // 2(N+1)
    int* eslot = rs + 2 * (N_NODES + 1);   // 2E
    int* iend  = eslot + 2 * N_EDGES;
    float* Opart = (float*)(((uintptr_t)iend + 15) & ~(uintptr_t)15);

    size_t base_bytes = (size_t)((char*)Opart - (char*)d_ws);
    size_t per_split  = (size_t)NHEADS * NPAD * (H + 2) * sizeof(float);
    int NS = 2;
    if (ws_size >= base_bytes + 4 * per_split + (1u << 20)) NS = 4;
    float* mlpart = Opart + (size_t)NS * NHEADS * NPAD * H;
    int tps = (NTILES + NS - 1) / NS;

    const int gN = (N_NODES + 255) / 256;
    const int gE = (N_EDGES + 255) / 256;

    // ---- CSR build (both graphs per launch) ----
    zero_ints<<<(4 * N_NODES + 255) / 256, 256, 0, stream>>>(cnt, 4 * N_NODES);
    hist2<<<dim3(gE, 2), 256, 0, stream>>>(e_rest, e_rig, cnt);
    scan2<<<2, 1024, 0, stream>>>(cnt, rs);
    dinv_kernel<<<(2 * N_NODES + 255) / 256, 256, 0, stream>>>(cnt, dinv, 2 * N_NODES);
    place2<<<dim3(gE, 2), 256, 0, stream>>>(e_rest, e_rig, rs, cur, eslot);

    float* hw_r = hw, * hw_g = hw + NH;
    float* ha_r = ha, * ha_g = ha + NH;
    float* hb_r = hb, * hb_g = hb + NH;

    // L1
    gcn_gemm2<<<dim3(N_NODES / 16, 2), 256, 0, stream>>>(x_rest, x_rig, Wr0, Wg0, hw_r, hw_g, 3);
    gather2<<<dim3(N_NODES, 2), H, 0, stream>>>(e_rest, e_rig, eslot, rs, hw_r, hw_g, dinv,
                                                br0, bg0, ha_r, ha_g, H, H);
    // L2
    gcn_gemm2<<<dim3(N_NODES / 16, 2), 256, 0, stream>>>(ha_r, ha_g, Wr, Wg, hw_r, hw_g, H);
    gather2<<<dim3(N_NODES, 2), H, 0, stream>>>(e_rest, e_rig, eslot, rs, hw_r, hw_g, dinv,
                                                br, bg, hb_r, hb_g, H, H);
    // L3: resting -> hcat cols 0:128 (stride 640); rigid -> xg (stride 128)
    gcn_gemm2<<<dim3(N_NODES / 16, 2), 256, 0, stream>>>(hb_r, hb_g, Wr + H * H, Wg + H * H,
                                                         hw_r, hw_g, H);
    gather2<<<dim3(N_NODES, 2), H, 0, stream>>>(e_rest, e_rig, eslot, rs, hw_r, hw_g, dinv,
                                                br + H, bg + H, hcat, xg, HCAT, H);

    // ---- attention ----
    qk_kernel2<<<dim3(N_NODES / 16, NHEADS), 256, 0, stream>>>(hcat, HCAT, xg, Wa, ba,
                                                               Qh, Ql, Khs, Kls);
    zero_pad_k<<<(NHEADS * 16 * H + 255) / 256, 256, 0, stream>>>(Khs, Kls);
    cvt_vt<<<NTILES, 128, 0, stream>>>(xg, Vth, Vtl);
    attn_mfma3<<<dim3(47, NHEADS, NS), 256, 0, stream>>>(Qh, Ql, Khs, Kls, Vth, Vtl,
                                                         Opart, mlpart, tps);
    attn_combine<<<(NHEADS * N_NODES * (H / 4) + 255) / 256, 256, 0, stream>>>(Opart, mlpart,
                                                                               hcat, NS);

    // ---- decoder ----
    decoder<<<N_NODES / 8, 256, 0, stream>>>(hcat, Wd0, bd0, Wd, bd, Wout, bout, out);
}